// Round 1
// baseline (2542.041 us; speedup 1.0000x reference)
//
#include <hip/hip_runtime.h>

#define NN 20000
#define NE 320000
#define HD 128
#define IND 16
#define OUTD 16
#define NL 4
#define LN_EPS 1e-5f

typedef __attribute__((ext_vector_type(8))) short bf16x8;
typedef __attribute__((ext_vector_type(4))) float f32x4;

__device__ __forceinline__ unsigned short f2b(float f) {
  union { float f; unsigned int u; } v; v.f = f;
  unsigned int r = v.u + 0x7FFFu + ((v.u >> 16) & 1u);
  return (unsigned short)(r >> 16);
}

// ---------------- small prep kernels ----------------

__global__ void prep_zero_k(const float* __restrict__ xin, float* __restrict__ xf,
                            float* __restrict__ aggh, float* __restrict__ aggx,
                            float* __restrict__ cnt) {
  int i = blockIdx.x * 256 + threadIdx.x;
  if (i < NN * HD) aggh[i] = 0.f;
  if (i < NN * 3) { aggx[i] = 0.f; xf[i] = xin[i]; }
  if (i < NN) cnt[i] = 0.f;
}

__global__ void count_k(const int* __restrict__ edges, float* __restrict__ cnt) {
  int e = blockIdx.x * 256 + threadIdx.x;
  if (e < NE) atomicAdd(&cnt[edges[e]], 1.f);
}

__global__ void inv_k(float* __restrict__ cnt) {
  int n = blockIdx.x * 256 + threadIdx.x;
  if (n < NN) { float c = cnt[n]; cnt[n] = (c > 0.f) ? 1.f / c : 0.f; }
}

// weights: src f32 [NL][Kreal][128] -> dst bf16 tiled [NL][KT][128][32] (transposed, zero-padded K)
__global__ void prep_w_k(const float* __restrict__ src, unsigned short* __restrict__ dst,
                         int KT, int Kreal) {
  int i = blockIdx.x * 256 + threadIdx.x;
  int total = NL * KT * 4096;
  if (i >= total) return;
  int kk = i & 31;
  int c = (i >> 5) & 127;
  int lkt = i >> 12;            // l*KT + kt
  int kt = lkt % KT;
  int l = lkt / KT;
  int k = kt * 32 + kk;
  float v = (k < Kreal) ? src[((size_t)l * Kreal + k) * HD + c] : 0.f;
  dst[i] = f2b(v);
}

__global__ void emb_k(const float* __restrict__ hin, const float* __restrict__ w,
                      const float* __restrict__ b, float* __restrict__ hf,
                      unsigned short* __restrict__ hb) {
  int i = blockIdx.x * 256 + threadIdx.x;
  if (i >= NN * HD) return;
  int n = i >> 7, c = i & 127;
  float acc = b[c];
#pragma unroll
  for (int k = 0; k < IND; ++k) acc += hin[n * IND + k] * w[k * HD + c];
  hf[i] = acc;
  hb[i] = f2b(acc);
}

__global__ void prepd_k(const float* __restrict__ xf, const int* __restrict__ edges,
                        const float* __restrict__ ea, float* __restrict__ dvec,
                        unsigned short* __restrict__ e8) {
  int e = blockIdx.x * 256 + threadIdx.x;
  if (e >= NE) return;
  int j = edges[e], i = edges[NE + e];
  float dx = xf[i * 3 + 0] - xf[j * 3 + 0];
  float dy = xf[i * 3 + 1] - xf[j * 3 + 1];
  float dz = xf[i * 3 + 2] - xf[j * 3 + 2];
  float d2 = dx * dx + dy * dy + dz * dz;
  dvec[e * 4 + 0] = dx; dvec[e * 4 + 1] = dy; dvec[e * 4 + 2] = dz; dvec[e * 4 + 3] = d2;
  e8[e * 8 + 0] = f2b(d2);
#pragma unroll
  for (int a = 0; a < 4; ++a) e8[e * 8 + 1 + a] = f2b(ea[e * 4 + a]);
  e8[e * 8 + 5] = 0; e8[e * 8 + 6] = 0; e8[e * 8 + 7] = 0;
}

__global__ void nodefix_k(float* __restrict__ xf, float* __restrict__ aggx,
                          const float* __restrict__ cinv, float* __restrict__ aggh) {
  int i = blockIdx.x * 256 + threadIdx.x;
  if (i >= NN * HD) return;
  aggh[i] = 0.f;
  int n = i >> 7, c = i & 127;
  if (c < 3) {
    xf[n * 3 + c] += aggx[n * 3 + c] * cinv[n];
    aggx[n * 3 + c] = 0.f;
  }
}

__global__ void outproj_k(const float* __restrict__ hf, const float* __restrict__ w,
                          const float* __restrict__ b, float* __restrict__ out) {
  int i = blockIdx.x * 256 + threadIdx.x;
  if (i >= NN * OUTD) return;
  int n = i >> 4, o = i & 15;
  float acc = b[o];
#pragma unroll 8
  for (int k = 0; k < HD; ++k) acc += hf[(size_t)n * HD + k] * w[k * OUTD + o];
  out[NN * 3 + i] = acc;
}

__global__ void xcopy_k(const float* __restrict__ xf, float* __restrict__ out) {
  int i = blockIdx.x * 256 + threadIdx.x;
  if (i < NN * 3) out[i] = xf[i];
}

// ---------------- fused GEMM stages ----------------
// STAGE 1: edges, K=288 (h[i]|h[j]|d2|ea pad), LN+SiLU -> tbuf
// STAGE 2: edges, K=128 (tbuf), LN+SiLU -> tbuf (in place) + atomic agg_h
// STAGE 3: edges, K=128 (tbuf=mh), LN+SiLU, dot w4, atomic agg_x
// STAGE 4: nodes, K=256 (h|agg_h), LN+SiLU -> t3
// STAGE 5: nodes, K=128 (t3), +bias+resid -> hf, hb

struct GP {
  const unsigned short* Asrc;
  const unsigned short* hb;
  const unsigned short* e8;
  const int* edges;
  const float* hf;
  const float* aggh_r;
  const unsigned short* wt;
  const float* bias;
  const float* g;
  const float* bb;
  unsigned short* outb;
  float* aggh_w;
  float* aggx_w;
  const float* w4;
  const float* b4p;
  const float* dvec;
  float* hf_out;
  unsigned short* hb_out;
  int M;
};

#define LDK 56  // padded K stride in LDS (bf16 elems): conflict-free ds_read_b128

template <int STAGE, int KT>
__global__ __launch_bounds__(256) void gemm_k(GP p) {
  __shared__ __align__(16) unsigned short Ash[128 * LDK];
  __shared__ __align__(16) unsigned short Bsh[128 * LDK];
  __shared__ int iidx[128];
  __shared__ int jidx[128];
  __shared__ float lnbuf[2][128][2];

  const int tid = threadIdx.x;
  const int lane = tid & 63;
  const int lid = lane & 15;
  const int q = lane >> 4;
  const int wave = tid >> 6;
  const int wm = wave >> 1;
  const int wn = wave & 1;
  const int row0 = blockIdx.x * 128;

  if constexpr (STAGE <= 3) {
    if (tid < 128) {
      iidx[tid] = p.edges[NE + row0 + tid];
      if (STAGE == 1) jidx[tid] = p.edges[row0 + tid];
    }
  }
  __syncthreads();

  f32x4 acc[4][4];
#pragma unroll
  for (int a = 0; a < 4; ++a)
#pragma unroll
    for (int b = 0; b < 4; ++b) acc[a][b] = (f32x4){0.f, 0.f, 0.f, 0.f};

  const int r = tid >> 1;
  const int ch = tid & 1;
  const int cb = ch << 4;

  for (int kt = 0; kt < KT; ++kt) {
    const int kb = kt << 5;
    uint4 av0 = {0, 0, 0, 0}, av1 = {0, 0, 0, 0};
    if constexpr (STAGE == 1) {
      const int k = kb + cb;
      if (k < HD) {
        const uint4* s = (const uint4*)(p.hb + (size_t)iidx[r] * HD + k);
        av0 = s[0]; av1 = s[1];
      } else if (k < 2 * HD) {
        const uint4* s = (const uint4*)(p.hb + (size_t)jidx[r] * HD + (k - HD));
        av0 = s[0]; av1 = s[1];
      } else if (ch == 0) {
        av0 = *(const uint4*)(p.e8 + (size_t)(row0 + r) * 8);
      }
    } else if constexpr (STAGE == 2 || STAGE == 3) {
      const uint4* s = (const uint4*)(p.Asrc + (size_t)(row0 + r) * HD + kb + cb);
      av0 = s[0]; av1 = s[1];
    } else if constexpr (STAGE == 4) {
      const int n = row0 + r;
      if (n < p.M) {
        const int k = kb + cb;
        const float* s = (k < HD) ? (p.hf + (size_t)n * HD + k)
                                  : (p.aggh_r + (size_t)n * HD + (k - HD));
        unsigned short tmp[16];
#pragma unroll
        for (int t = 0; t < 16; ++t) tmp[t] = f2b(s[t]);
        av0 = *(const uint4*)&tmp[0];
        av1 = *(const uint4*)&tmp[8];
      }
    } else {
      const int n = row0 + r;
      if (n < p.M) {
        const uint4* s = (const uint4*)(p.Asrc + (size_t)n * HD + kb + cb);
        av0 = s[0]; av1 = s[1];
      }
    }
    const uint4* bs = (const uint4*)(p.wt + (size_t)kt * 4096 + r * 32 + cb);
    const uint4 bv0 = bs[0];
    const uint4 bv1 = bs[1];

    __syncthreads();
    *(uint4*)&Ash[r * LDK + cb] = av0;
    *(uint4*)&Ash[r * LDK + cb + 8] = av1;
    *(uint4*)&Bsh[r * LDK + cb] = bv0;
    *(uint4*)&Bsh[r * LDK + cb + 8] = bv1;
    __syncthreads();

    bf16x8 af[4], bq[4];
#pragma unroll
    for (int mf = 0; mf < 4; ++mf)
      af[mf] = *(const bf16x8*)&Ash[(wm * 64 + mf * 16 + lid) * LDK + q * 8];
#pragma unroll
    for (int nf = 0; nf < 4; ++nf)
      bq[nf] = *(const bf16x8*)&Bsh[(wn * 64 + nf * 16 + lid) * LDK + q * 8];
#pragma unroll
    for (int mf = 0; mf < 4; ++mf)
#pragma unroll
      for (int nf = 0; nf < 4; ++nf)
        acc[mf][nf] = __builtin_amdgcn_mfma_f32_16x16x32_bf16(af[mf], bq[nf], acc[mf][nf], 0, 0, 0);
  }

  // per-lane column constants
  float biasc[4], gc[4], bbc[4], w4c[4];
#pragma unroll
  for (int nf = 0; nf < 4; ++nf) {
    const int c = wn * 64 + nf * 16 + lid;
    biasc[nf] = p.bias[c];
    if constexpr (STAGE <= 4) { gc[nf] = p.g[c]; bbc[nf] = p.bb[c]; }
    if constexpr (STAGE == 3) w4c[nf] = p.w4[c];
  }
#pragma unroll
  for (int mf = 0; mf < 4; ++mf)
#pragma unroll
    for (int nf = 0; nf < 4; ++nf)
#pragma unroll
      for (int rg = 0; rg < 4; ++rg) acc[mf][nf][rg] += biasc[nf];

  if constexpr (STAGE <= 4) {
    // row LayerNorm over 128 cols (this wave holds 64 cols; pair with wn^1 via LDS)
    float s_[4][4], ss_[4][4];
#pragma unroll
    for (int mf = 0; mf < 4; ++mf)
#pragma unroll
      for (int rg = 0; rg < 4; ++rg) {
        float a = 0.f, b = 0.f;
#pragma unroll
        for (int nf = 0; nf < 4; ++nf) { float v = acc[mf][nf][rg]; a += v; b += v * v; }
        s_[mf][rg] = a; ss_[mf][rg] = b;
      }
#pragma unroll
    for (int m = 1; m < 16; m <<= 1) {
#pragma unroll
      for (int mf = 0; mf < 4; ++mf)
#pragma unroll
        for (int rg = 0; rg < 4; ++rg) {
          s_[mf][rg] += __shfl_xor(s_[mf][rg], m);
          ss_[mf][rg] += __shfl_xor(ss_[mf][rg], m);
        }
    }
    if (lid == 0) {
#pragma unroll
      for (int mf = 0; mf < 4; ++mf)
#pragma unroll
        for (int rg = 0; rg < 4; ++rg) {
          const int rl = wm * 64 + mf * 16 + q * 4 + rg;
          lnbuf[wn][rl][0] = s_[mf][rg];
          lnbuf[wn][rl][1] = ss_[mf][rg];
        }
    }
    __syncthreads();
    float mean_[4][4], rstd_[4][4];
#pragma unroll
    for (int mf = 0; mf < 4; ++mf)
#pragma unroll
      for (int rg = 0; rg < 4; ++rg) {
        const int rl = wm * 64 + mf * 16 + q * 4 + rg;
        const float t0 = lnbuf[0][rl][0] + lnbuf[1][rl][0];
        const float t1 = lnbuf[0][rl][1] + lnbuf[1][rl][1];
        const float mu = t0 * (1.f / HD);
        const float var = t1 * (1.f / HD) - mu * mu;
        mean_[mf][rg] = mu;
        rstd_[mf][rg] = rsqrtf(var + LN_EPS);
      }
#pragma unroll
    for (int mf = 0; mf < 4; ++mf)
#pragma unroll
      for (int nf = 0; nf < 4; ++nf)
#pragma unroll
        for (int rg = 0; rg < 4; ++rg) {
          float v = acc[mf][nf][rg];
          v = (v - mean_[mf][rg]) * rstd_[mf][rg] * gc[nf] + bbc[nf];
          acc[mf][nf][rg] = v / (1.f + __expf(-v));  // SiLU
        }
  }

  if constexpr (STAGE == 1 || STAGE == 2 || STAGE == 4) {
#pragma unroll
    for (int mf = 0; mf < 4; ++mf)
#pragma unroll
      for (int rg = 0; rg < 4; ++rg) {
        const int rl = wm * 64 + mf * 16 + q * 4 + rg;
        const int gr = row0 + rl;
        if (STAGE == 4 && gr >= p.M) continue;
#pragma unroll
        for (int nf = 0; nf < 4; ++nf) {
          const int c = wn * 64 + nf * 16 + lid;
          p.outb[(size_t)gr * HD + c] = f2b(acc[mf][nf][rg]);
        }
        if constexpr (STAGE == 2) {
          const int ii = iidx[rl];
#pragma unroll
          for (int nf = 0; nf < 4; ++nf) {
            const int c = wn * 64 + nf * 16 + lid;
            atomicAdd(&p.aggh_w[(size_t)ii * HD + c], acc[mf][nf][rg]);
          }
        }
      }
  }

  if constexpr (STAGE == 3) {
    float dp[4][4];
#pragma unroll
    for (int mf = 0; mf < 4; ++mf)
#pragma unroll
      for (int rg = 0; rg < 4; ++rg) {
        float a = 0.f;
#pragma unroll
        for (int nf = 0; nf < 4; ++nf) a += acc[mf][nf][rg] * w4c[nf];
        dp[mf][rg] = a;
      }
#pragma unroll
    for (int m = 1; m < 16; m <<= 1) {
#pragma unroll
      for (int mf = 0; mf < 4; ++mf)
#pragma unroll
        for (int rg = 0; rg < 4; ++rg) dp[mf][rg] += __shfl_xor(dp[mf][rg], m);
    }
    __syncthreads();
    if (lid == 0) {
#pragma unroll
      for (int mf = 0; mf < 4; ++mf)
#pragma unroll
        for (int rg = 0; rg < 4; ++rg)
          lnbuf[wn][wm * 64 + mf * 16 + q * 4 + rg][0] = dp[mf][rg];
    }
    __syncthreads();
    if (wn == 0 && lid == 0) {
      const float b4 = p.b4p[0];
#pragma unroll
      for (int mf = 0; mf < 4; ++mf)
#pragma unroll
        for (int rg = 0; rg < 4; ++rg) {
          const int rl = wm * 64 + mf * 16 + q * 4 + rg;
          const float sc = lnbuf[0][rl][0] + lnbuf[1][rl][0] + b4;
          const int e = row0 + rl;
          const int ii = iidx[rl];
          const float* d = p.dvec + (size_t)e * 4;
          atomicAdd(&p.aggx_w[ii * 3 + 0], d[0] * sc);
          atomicAdd(&p.aggx_w[ii * 3 + 1], d[1] * sc);
          atomicAdd(&p.aggx_w[ii * 3 + 2], d[2] * sc);
        }
    }
  }

  if constexpr (STAGE == 5) {
#pragma unroll
    for (int mf = 0; mf < 4; ++mf)
#pragma unroll
      for (int rg = 0; rg < 4; ++rg) {
        const int rl = wm * 64 + mf * 16 + q * 4 + rg;
        const int n = row0 + rl;
        if (n < p.M) {
#pragma unroll
          for (int nf = 0; nf < 4; ++nf) {
            const int c = wn * 64 + nf * 16 + lid;
            const float v = acc[mf][nf][rg] + p.hf[(size_t)n * HD + c];
            p.hf_out[(size_t)n * HD + c] = v;
            p.hb_out[(size_t)n * HD + c] = f2b(v);
          }
        }
      }
  }
}

// ---------------- host ----------------

extern "C" void kernel_launch(void* const* d_in, const int* in_sizes, int n_in,
                              void* d_out, int out_size, void* d_ws, size_t ws_size,
                              hipStream_t stream) {
  (void)in_sizes; (void)n_in; (void)out_size; (void)ws_size;
  const float* x_in = (const float*)d_in[0];
  const float* h_in = (const float*)d_in[1];
  const int* edges = (const int*)d_in[2];
  const float* eattr = (const float*)d_in[3];
  const float* emb_w = (const float*)d_in[4];
  const float* emb_b = (const float*)d_in[5];
  const float* out_w = (const float*)d_in[6];
  const float* out_b = (const float*)d_in[7];
  const float* pe_w1 = (const float*)d_in[8];
  const float* pe_b1 = (const float*)d_in[9];
  const float* pe_g1 = (const float*)d_in[10];
  const float* pe_bb1 = (const float*)d_in[11];
  const float* pe_w2 = (const float*)d_in[12];
  const float* pe_b2 = (const float*)d_in[13];
  const float* pe_g2 = (const float*)d_in[14];
  const float* pe_bb2 = (const float*)d_in[15];
  const float* px_w1 = (const float*)d_in[16];
  const float* px_b1 = (const float*)d_in[17];
  const float* px_g1 = (const float*)d_in[18];
  const float* px_bb1 = (const float*)d_in[19];
  const float* px_w2 = (const float*)d_in[20];
  const float* px_b2 = (const float*)d_in[21];
  const float* ph_w1 = (const float*)d_in[22];
  const float* ph_b1 = (const float*)d_in[23];
  const float* ph_g1 = (const float*)d_in[24];
  const float* ph_bb1 = (const float*)d_in[25];
  const float* ph_w2 = (const float*)d_in[26];
  const float* ph_b2 = (const float*)d_in[27];
  float* out = (float*)d_out;

  char* ws = (char*)d_ws;
  size_t off = 0;
  auto alloc = [&](size_t bytes) -> void* {
    void* ptr = ws + off;
    off = (off + bytes + 255) & ~(size_t)255;
    return ptr;
  };
  float* hf = (float*)alloc((size_t)NN * HD * 4);
  unsigned short* hb = (unsigned short*)alloc((size_t)NN * HD * 2);
  float* aggh = (float*)alloc((size_t)NN * HD * 4);
  float* aggx = (float*)alloc((size_t)NN * 3 * 4);
  float* xf = (float*)alloc((size_t)NN * 3 * 4);
  float* cinv = (float*)alloc((size_t)NN * 4);
  float* dvec = (float*)alloc((size_t)NE * 4 * 4);
  unsigned short* e8 = (unsigned short*)alloc((size_t)NE * 8 * 2);
  unsigned short* tbuf = (unsigned short*)alloc((size_t)NE * HD * 2);
  unsigned short* t3 = (unsigned short*)alloc((size_t)NN * HD * 2);
  unsigned short* w1t = (unsigned short*)alloc((size_t)NL * 9 * 4096 * 2);
  unsigned short* w2t = (unsigned short*)alloc((size_t)NL * 4 * 4096 * 2);
  unsigned short* w3t = (unsigned short*)alloc((size_t)NL * 4 * 4096 * 2);
  unsigned short* w4t = (unsigned short*)alloc((size_t)NL * 8 * 4096 * 2);
  unsigned short* w5t = (unsigned short*)alloc((size_t)NL * 4 * 4096 * 2);

  prep_zero_k<<<(NN * HD + 255) / 256, 256, 0, stream>>>(x_in, xf, aggh, aggx, cinv);
  count_k<<<(NE + 255) / 256, 256, 0, stream>>>(edges, cinv);
  inv_k<<<(NN + 255) / 256, 256, 0, stream>>>(cinv);
  prep_w_k<<<(NL * 9 * 4096 + 255) / 256, 256, 0, stream>>>(pe_w1, w1t, 9, 261);
  prep_w_k<<<(NL * 4 * 4096 + 255) / 256, 256, 0, stream>>>(pe_w2, w2t, 4, 128);
  prep_w_k<<<(NL * 4 * 4096 + 255) / 256, 256, 0, stream>>>(px_w1, w3t, 4, 128);
  prep_w_k<<<(NL * 8 * 4096 + 255) / 256, 256, 0, stream>>>(ph_w1, w4t, 8, 256);
  prep_w_k<<<(NL * 4 * 4096 + 255) / 256, 256, 0, stream>>>(ph_w2, w5t, 4, 128);
  emb_k<<<(NN * HD + 255) / 256, 256, 0, stream>>>(h_in, emb_w, emb_b, hf, hb);

  const int egrid = NE / 128;          // 2500
  const int ngrid = (NN + 127) / 128;  // 157

  for (int l = 0; l < NL; ++l) {
    prepd_k<<<(NE + 255) / 256, 256, 0, stream>>>(xf, edges, eattr, dvec, e8);
    {
      GP p{}; p.hb = hb; p.e8 = e8; p.edges = edges;
      p.wt = w1t + (size_t)l * 9 * 4096;
      p.bias = pe_b1 + l * HD; p.g = pe_g1 + l * HD; p.bb = pe_bb1 + l * HD;
      p.outb = tbuf; p.M = NE;
      gemm_k<1, 9><<<egrid, 256, 0, stream>>>(p);
    }
    {
      GP p{}; p.Asrc = tbuf; p.edges = edges;
      p.wt = w2t + (size_t)l * 4 * 4096;
      p.bias = pe_b2 + l * HD; p.g = pe_g2 + l * HD; p.bb = pe_bb2 + l * HD;
      p.outb = tbuf; p.aggh_w = aggh; p.M = NE;
      gemm_k<2, 4><<<egrid, 256, 0, stream>>>(p);
    }
    {
      GP p{}; p.Asrc = tbuf; p.edges = edges;
      p.wt = w3t + (size_t)l * 4 * 4096;
      p.bias = px_b1 + l * HD; p.g = px_g1 + l * HD; p.bb = px_bb1 + l * HD;
      p.w4 = px_w2 + l * HD; p.b4p = px_b2 + l; p.dvec = dvec; p.aggx_w = aggx; p.M = NE;
      gemm_k<3, 4><<<egrid, 256, 0, stream>>>(p);
    }
    {
      GP p{}; p.hf = hf; p.aggh_r = aggh;
      p.wt = w4t + (size_t)l * 8 * 4096;
      p.bias = ph_b1 + l * HD; p.g = ph_g1 + l * HD; p.bb = ph_bb1 + l * HD;
      p.outb = t3; p.M = NN;
      gemm_k<4, 8><<<ngrid, 256, 0, stream>>>(p);
    }
    {
      GP p{}; p.Asrc = t3;
      p.wt = w5t + (size_t)l * 4 * 4096;
      p.bias = ph_b2 + l * HD; p.hf = hf; p.hf_out = hf; p.hb_out = hb; p.M = NN;
      gemm_k<5, 4><<<ngrid, 256, 0, stream>>>(p);
    }
    nodefix_k<<<(NN * HD + 255) / 256, 256, 0, stream>>>(xf, aggx, cinv, aggh);
  }

  outproj_k<<<(NN * OUTD + 255) / 256, 256, 0, stream>>>(hf, out_w, out_b, out);
  xcopy_k<<<(NN * 3 + 255) / 256, 256, 0, stream>>>(xf, out);
}

// Round 5
// 1947.060 us; speedup vs baseline: 1.3056x; 1.3056x over previous
//
#include <hip/hip_runtime.h>

#define NN 20000
#define NE 320000
#define HD 128
#define IND 16
#define OUTD 16
#define NL 4
#define LN_EPS 1e-5f
#define LDA 136  // A-tile LDS stride in shorts (272B = 17*16B: keeps b128 16B-aligned)
#define LDB 36   // B-tile LDS stride in shorts

typedef __attribute__((ext_vector_type(8))) short bf16x8;
typedef __attribute__((ext_vector_type(4))) float f32x4;

__device__ __forceinline__ unsigned short f2b(float f) {
  union { float f; unsigned int u; } v; v.f = f;
  unsigned int r = v.u + 0x7FFFu + ((v.u >> 16) & 1u);
  return (unsigned short)(r >> 16);
}
__device__ __forceinline__ float b2f(unsigned int lo16) {
  union { unsigned int u; float f; } v; v.u = lo16 << 16; return v.f;
}

// ---------------- prep kernels ----------------

__global__ void prep_zero_k(const float* __restrict__ xin, float* __restrict__ xf,
                            float* __restrict__ cnt, int* __restrict__ deg) {
  int i = blockIdx.x * 256 + threadIdx.x;
  if (i < NN * 3) xf[i] = xin[i];
  if (i < NN) { cnt[i] = 0.f; deg[i] = 0; }
}

__global__ void count_k(const int* __restrict__ edges, float* __restrict__ cnt,
                        int* __restrict__ deg) {
  int e = blockIdx.x * 256 + threadIdx.x;
  if (e < NE) {
    atomicAdd(&cnt[edges[e]], 1.f);        // out-degree by src (divisor c)
    atomicAdd(&deg[edges[NE + e]], 1);     // in-degree by dst (CSR)
  }
}

__global__ void inv_k(float* __restrict__ cnt) {
  int n = blockIdx.x * 256 + threadIdx.x;
  if (n < NN) { float c = cnt[n]; cnt[n] = (c > 0.f) ? 1.f / c : 0.f; }
}

__global__ void scan_k(const int* __restrict__ deg, int* __restrict__ rowptr,
                       int* __restrict__ cursor) {
  __shared__ int part[256];
  const int tid = threadIdx.x;
  const int base = tid * 79;
  int s = 0;
  for (int t = 0; t < 79; ++t) { int idx = base + t; if (idx < NN) s += deg[idx]; }
  part[tid] = s;
  __syncthreads();
  for (int off = 1; off < 256; off <<= 1) {
    int v = (tid >= off) ? part[tid - off] : 0;
    __syncthreads();
    part[tid] += v;
    __syncthreads();
  }
  int run = (tid == 0) ? 0 : part[tid - 1];
  for (int t = 0; t < 79; ++t) {
    int idx = base + t;
    if (idx < NN) { rowptr[idx] = run; cursor[idx] = run; run += deg[idx]; }
  }
  if (tid == 255) rowptr[NN] = run;
}

__global__ void scatter_k(const int* __restrict__ edges, int* __restrict__ cursor,
                          int* __restrict__ eids) {
  int e = blockIdx.x * 256 + threadIdx.x;
  if (e < NE) {
    int d = edges[NE + e];
    int pos = atomicAdd(&cursor[d], 1);
    eids[pos] = e;
  }
}

// weights: src f32 [NL][Kreal][128] -> dst bf16 tiled [NL][KT][128][32]
__global__ void prep_w_k(const float* __restrict__ src, unsigned short* __restrict__ dst,
                         int KT, int Kreal) {
  int i = blockIdx.x * 256 + threadIdx.x;
  int total = NL * KT * 4096;
  if (i >= total) return;
  int kk = i & 31;
  int c = (i >> 5) & 127;
  int lkt = i >> 12;
  int kt = lkt % KT;
  int l = lkt / KT;
  int k = kt * 32 + kk;
  float v = (k < Kreal) ? src[((size_t)l * Kreal + k) * HD + c] : 0.f;
  dst[i] = f2b(v);
}

__global__ void emb_k(const float* __restrict__ hin, const float* __restrict__ w,
                      const float* __restrict__ b, float* __restrict__ hf,
                      unsigned short* __restrict__ hb) {
  int i = blockIdx.x * 256 + threadIdx.x;
  if (i >= NN * HD) return;
  int n = i >> 7, c = i & 127;
  float acc = b[c];
#pragma unroll
  for (int k = 0; k < IND; ++k) acc += hin[n * IND + k] * w[k * HD + c];
  hf[i] = acc;
  hb[i] = f2b(acc);
}

__global__ void prepd_k(const float* __restrict__ xf, const int* __restrict__ edges,
                        const float* __restrict__ ea, float* __restrict__ dvec,
                        unsigned short* __restrict__ e8) {
  int e = blockIdx.x * 256 + threadIdx.x;
  if (e >= NE) return;
  int j = edges[e], i = edges[NE + e];
  float dx = xf[i * 3 + 0] - xf[j * 3 + 0];
  float dy = xf[i * 3 + 1] - xf[j * 3 + 1];
  float dz = xf[i * 3 + 2] - xf[j * 3 + 2];
  float d2 = dx * dx + dy * dy + dz * dz;
  dvec[e * 4 + 0] = dx; dvec[e * 4 + 1] = dy; dvec[e * 4 + 2] = dz; dvec[e * 4 + 3] = d2;
  e8[e * 8 + 0] = f2b(d2);
#pragma unroll
  for (int a = 0; a < 4; ++a) e8[e * 8 + 1 + a] = f2b(ea[e * 4 + a]);
  e8[e * 8 + 5] = 0; e8[e * 8 + 6] = 0; e8[e * 8 + 7] = 0;
}

__global__ void outproj_k(const float* __restrict__ hf, const float* __restrict__ w,
                          const float* __restrict__ b, float* __restrict__ out) {
  int i = blockIdx.x * 256 + threadIdx.x;
  if (i >= NN * OUTD) return;
  int n = i >> 4, o = i & 15;
  float acc = b[o];
#pragma unroll 8
  for (int k = 0; k < HD; ++k) acc += hf[(size_t)n * HD + k] * w[k * OUTD + o];
  out[NN * 3 + i] = acc;
}

__global__ void xcopy_k(const float* __restrict__ xf, float* __restrict__ out) {
  int i = blockIdx.x * 256 + threadIdx.x;
  if (i < NN * 3) out[i] = xf[i];
}

// ---------------- CSR gather: agg_h + agg_x + x update ----------------

__global__ __launch_bounds__(256) void gather_k(const unsigned short* __restrict__ tbuf,
                                                const float* __restrict__ sc,
                                                const float* __restrict__ dvec,
                                                const int* __restrict__ rowptr,
                                                const int* __restrict__ eids,
                                                const float* __restrict__ cinv,
                                                float* __restrict__ aggh,
                                                float* __restrict__ xf) {
  const int n = blockIdx.x * 4 + (threadIdx.x >> 6);
  if (n >= NN) return;
  const int lane = threadIdx.x & 63;
  const int s = rowptr[n], e = rowptr[n + 1];
  float a0 = 0.f, a1 = 0.f, xa = 0.f;
  for (int t = s; t < e; ++t) {
    const int eid = eids[t];
    const unsigned int v = *(const unsigned int*)(tbuf + (size_t)eid * HD + lane * 2);
    a0 += b2f(v & 0xffffu);
    a1 += b2f(v >> 16);
    if (lane < 3) xa += dvec[(size_t)eid * 4 + lane] * sc[eid];
  }
  aggh[(size_t)n * HD + lane * 2] = a0;
  aggh[(size_t)n * HD + lane * 2 + 1] = a1;
  if (lane < 3) xf[n * 3 + lane] += xa * cinv[n];
}

// ---------------- shared GEMM pieces ----------------

__device__ __forceinline__ void mfma_step(const unsigned short* At, int colbase,
                                          const unsigned short* Bs, f32x4 (&acc)[4][4],
                                          int wm, int wn, int lid, int q) {
  bf16x8 af[4], bq[4];
#pragma unroll
  for (int mf = 0; mf < 4; ++mf)
    af[mf] = *(const bf16x8*)&At[(wm * 64 + mf * 16 + lid) * LDA + colbase + q * 8];
#pragma unroll
  for (int nf = 0; nf < 4; ++nf)
    bq[nf] = *(const bf16x8*)&Bs[(wn * 64 + nf * 16 + lid) * LDB + q * 8];
#pragma unroll
  for (int mf = 0; mf < 4; ++mf)
#pragma unroll
    for (int nf = 0; nf < 4; ++nf)
      acc[mf][nf] = __builtin_amdgcn_mfma_f32_16x16x32_bf16(af[mf], bq[nf], acc[mf][nf], 0, 0, 0);
}

// bias + row-LayerNorm(128) + SiLU, in place. Contains one __syncthreads.
__device__ __forceinline__ void ln_silu(f32x4 (&acc)[4][4], float (*lnb)[128][2],
                                        const float* bias, const float* g, const float* bb,
                                        int wm, int wn, int lid, int q) {
  float biasc[4], gc[4], bbc[4];
#pragma unroll
  for (int nf = 0; nf < 4; ++nf) {
    const int c = wn * 64 + nf * 16 + lid;
    biasc[nf] = bias[c]; gc[nf] = g[c]; bbc[nf] = bb[c];
  }
#pragma unroll
  for (int mf = 0; mf < 4; ++mf)
#pragma unroll
    for (int nf = 0; nf < 4; ++nf)
#pragma unroll
      for (int rg = 0; rg < 4; ++rg) acc[mf][nf][rg] += biasc[nf];

  float s_[4][4], ss_[4][4];
#pragma unroll
  for (int mf = 0; mf < 4; ++mf)
#pragma unroll
    for (int rg = 0; rg < 4; ++rg) {
      float a = 0.f, b = 0.f;
#pragma unroll
      for (int nf = 0; nf < 4; ++nf) { float v = acc[mf][nf][rg]; a += v; b += v * v; }
      s_[mf][rg] = a; ss_[mf][rg] = b;
    }
#pragma unroll
  for (int m = 1; m < 16; m <<= 1) {
#pragma unroll
    for (int mf = 0; mf < 4; ++mf)
#pragma unroll
      for (int rg = 0; rg < 4; ++rg) {
        s_[mf][rg] += __shfl_xor(s_[mf][rg], m);
        ss_[mf][rg] += __shfl_xor(ss_[mf][rg], m);
      }
  }
  if (lid == 0) {
#pragma unroll
    for (int mf = 0; mf < 4; ++mf)
#pragma unroll
      for (int rg = 0; rg < 4; ++rg) {
        const int rl = wm * 64 + mf * 16 + q * 4 + rg;
        lnb[wn][rl][0] = s_[mf][rg];
        lnb[wn][rl][1] = ss_[mf][rg];
      }
  }
  __syncthreads();
#pragma unroll
  for (int mf = 0; mf < 4; ++mf)
#pragma unroll
    for (int rg = 0; rg < 4; ++rg) {
      const int rl = wm * 64 + mf * 16 + q * 4 + rg;
      const float t0 = lnb[0][rl][0] + lnb[1][rl][0];
      const float t1 = lnb[0][rl][1] + lnb[1][rl][1];
      const float mu = t0 * (1.f / HD);
      const float var = t1 * (1.f / HD) - mu * mu;
      const float rstd = rsqrtf(var + LN_EPS);
#pragma unroll
      for (int nf = 0; nf < 4; ++nf) {
        float v = acc[mf][nf][rg];
        v = (v - mu) * rstd * gc[nf] + bbc[nf];
        acc[mf][nf][rg] = v / (1.f + __expf(-v));
      }
    }
}

// write C fragments (bf16) into the full A-tile (row=C-row, col=C-col)
__device__ __forceinline__ void write_tile(const f32x4 (&acc)[4][4], unsigned short* At,
                                           int wm, int wn, int lid, int q) {
#pragma unroll
  for (int mf = 0; mf < 4; ++mf)
#pragma unroll
    for (int rg = 0; rg < 4; ++rg) {
      const int row = wm * 64 + mf * 16 + q * 4 + rg;
#pragma unroll
      for (int nf = 0; nf < 4; ++nf) {
        const int col = wn * 64 + nf * 16 + lid;
        At[row * LDA + col] = f2b(acc[mf][nf][rg]);
      }
    }
}

// ---------------- fused edge kernel: GEMM1 -> LN/SiLU -> GEMM2 -> LN/SiLU
// -> (tbuf store) -> GEMM3 -> LN/SiLU -> dot(w4) -> sc ----------------

struct EP {
  const unsigned short* hb;
  const unsigned short* e8;
  const int* edges;
  const unsigned short *w1, *w2, *w3;
  const float *b1, *g1, *bb1, *b2, *g2, *bb2, *b3, *g3, *bb3;
  const float *w4, *b4;
  unsigned short* tbuf;
  float* sc;
};

__global__ __launch_bounds__(256) void edge_k(EP p) {
  __shared__ __align__(16) unsigned short At[128 * LDA];
  __shared__ __align__(16) unsigned short Bs[128 * LDB];
  __shared__ int iidx[128], jidx[128];
  __shared__ float lnb[2][128][2];

  const int tid = threadIdx.x, lane = tid & 63, lid = lane & 15, q = lane >> 4;
  const int wave = tid >> 6, wm = wave >> 1, wn = wave & 1;
  const int row0 = blockIdx.x * 128;
  const int r = tid >> 1, ch = tid & 1, cb = ch << 4;

  if (tid < 128) { iidx[tid] = p.edges[NE + row0 + tid]; jidx[tid] = p.edges[row0 + tid]; }
  __syncthreads();

  f32x4 acc[4][4];
#pragma unroll
  for (int a = 0; a < 4; ++a)
#pragma unroll
    for (int b = 0; b < 4; ++b) acc[a][b] = (f32x4){0.f, 0.f, 0.f, 0.f};

  // GEMM1: K=288, A staged per-ktile into At cols [0,32)
  for (int kt = 0; kt < 9; ++kt) {
    uint4 av0 = {0, 0, 0, 0}, av1 = {0, 0, 0, 0};
    const int k = kt * 32 + cb;
    if (k < HD) {
      const uint4* s = (const uint4*)(p.hb + (size_t)iidx[r] * HD + k);
      av0 = s[0]; av1 = s[1];
    } else if (k < 2 * HD) {
      const uint4* s = (const uint4*)(p.hb + (size_t)jidx[r] * HD + (k - HD));
      av0 = s[0]; av1 = s[1];
    } else if (ch == 0) {
      av0 = *(const uint4*)(p.e8 + (size_t)(row0 + r) * 8);
    }
    const uint4* bsrc = (const uint4*)(p.w1 + (size_t)kt * 4096 + r * 32 + cb);
    const uint4 bv0 = bsrc[0], bv1 = bsrc[1];
    __syncthreads();
    *(uint4*)&At[r * LDA + cb] = av0;
    *(uint4*)&At[r * LDA + cb + 8] = av1;
    *(uint4*)&Bs[r * LDB + cb] = bv0;
    *(uint4*)&Bs[r * LDB + cb + 8] = bv1;
    __syncthreads();
    mfma_step(At, 0, Bs, acc, wm, wn, lid, q);
  }
  ln_silu(acc, lnb, p.b1, p.g1, p.bb1, wm, wn, lid, q);
  write_tile(acc, At, wm, wn, lid, q);  // t -> At (all GEMM1 reads done at ln's barrier)

  // GEMM2: K=128 from At
#pragma unroll
  for (int a = 0; a < 4; ++a)
#pragma unroll
    for (int b = 0; b < 4; ++b) acc[a][b] = (f32x4){0.f, 0.f, 0.f, 0.f};
  for (int kt = 0; kt < 4; ++kt) {
    const uint4* bsrc = (const uint4*)(p.w2 + (size_t)kt * 4096 + r * 32 + cb);
    const uint4 bv0 = bsrc[0], bv1 = bsrc[1];
    __syncthreads();
    *(uint4*)&Bs[r * LDB + cb] = bv0;
    *(uint4*)&Bs[r * LDB + cb + 8] = bv1;
    __syncthreads();
    mfma_step(At, kt * 32, Bs, acc, wm, wn, lid, q);
  }
  ln_silu(acc, lnb, p.b2, p.g2, p.bb2, wm, wn, lid, q);
  write_tile(acc, At, wm, wn, lid, q);  // mh -> At
  __syncthreads();
  // coalesced mh copy-out to tbuf (16B granules)
#pragma unroll
  for (int c4 = 0; c4 < 8; ++c4) {
    const int idx = tid + c4 * 256;
    const int row = idx >> 4, sl = idx & 15;
    const uint4 v = *(const uint4*)&At[row * LDA + sl * 8];
    *(uint4*)(p.tbuf + (size_t)(row0 + row) * HD + sl * 8) = v;
  }

  // GEMM3: K=128 from At
#pragma unroll
  for (int a = 0; a < 4; ++a)
#pragma unroll
    for (int b = 0; b < 4; ++b) acc[a][b] = (f32x4){0.f, 0.f, 0.f, 0.f};
  for (int kt = 0; kt < 4; ++kt) {
    const uint4* bsrc = (const uint4*)(p.w3 + (size_t)kt * 4096 + r * 32 + cb);
    const uint4 bv0 = bsrc[0], bv1 = bsrc[1];
    __syncthreads();
    *(uint4*)&Bs[r * LDB + cb] = bv0;
    *(uint4*)&Bs[r * LDB + cb + 8] = bv1;
    __syncthreads();
    mfma_step(At, kt * 32, Bs, acc, wm, wn, lid, q);
  }
  ln_silu(acc, lnb, p.b3, p.g3, p.bb3, wm, wn, lid, q);

  // per-edge scalar: sc = dot(t2_row, w4) + b4
  float w4c[4];
#pragma unroll
  for (int nf = 0; nf < 4; ++nf) w4c[nf] = p.w4[wn * 64 + nf * 16 + lid];
  float dp[4][4];
#pragma unroll
  for (int mf = 0; mf < 4; ++mf)
#pragma unroll
    for (int rg = 0; rg < 4; ++rg) {
      float a = 0.f;
#pragma unroll
      for (int nf = 0; nf < 4; ++nf) a += acc[mf][nf][rg] * w4c[nf];
      dp[mf][rg] = a;
    }
#pragma unroll
  for (int m = 1; m < 16; m <<= 1) {
#pragma unroll
    for (int mf = 0; mf < 4; ++mf)
#pragma unroll
      for (int rg = 0; rg < 4; ++rg) dp[mf][rg] += __shfl_xor(dp[mf][rg], m);
  }
  __syncthreads();  // lnb reuse hazard: prior ln_silu readers must finish
  if (lid == 0) {
#pragma unroll
    for (int mf = 0; mf < 4; ++mf)
#pragma unroll
      for (int rg = 0; rg < 4; ++rg)
        lnb[wn][wm * 64 + mf * 16 + q * 4 + rg][0] = dp[mf][rg];
  }
  __syncthreads();
  if (tid < 128) p.sc[row0 + tid] = lnb[0][tid][0] + lnb[1][tid][0] + p.b4[0];
}

// ---------------- fused node kernel: GEMM4 -> LN/SiLU -> GEMM5 -> +bias+resid ----------------

struct NP {
  const float* hf;
  const float* aggh;
  const unsigned short *w4t, *w5t;
  const float *b1, *g1, *bb1, *b5;
  float* hf_out;
  unsigned short* hb_out;
};

__global__ __launch_bounds__(256) void node_k(NP p) {
  __shared__ __align__(16) unsigned short At[128 * LDA];
  __shared__ __align__(16) unsigned short Bs[128 * LDB];
  __shared__ float lnb[2][128][2];

  const int tid = threadIdx.x, lane = tid & 63, lid = lane & 15, q = lane >> 4;
  const int wave = tid >> 6, wm = wave >> 1, wn = wave & 1;
  const int row0 = blockIdx.x * 128;
  const int r = tid >> 1, ch = tid & 1, cb = ch << 4;

  f32x4 acc[4][4];
#pragma unroll
  for (int a = 0; a < 4; ++a)
#pragma unroll
    for (int b = 0; b < 4; ++b) acc[a][b] = (f32x4){0.f, 0.f, 0.f, 0.f};

  // GEMM4: K=256 ([h | agg_h]), A staged per-ktile into At cols [0,32)
  for (int kt = 0; kt < 8; ++kt) {
    uint4 av0 = {0, 0, 0, 0}, av1 = {0, 0, 0, 0};
    const int n = row0 + r;
    if (n < NN) {
      const int k = kt * 32 + cb;
      const float* s = (k < HD) ? (p.hf + (size_t)n * HD + k)
                                : (p.aggh + (size_t)n * HD + (k - HD));
      unsigned short tmp[16];
#pragma unroll
      for (int t = 0; t < 16; ++t) tmp[t] = f2b(s[t]);
      av0 = *(const uint4*)&tmp[0];
      av1 = *(const uint4*)&tmp[8];
    }
    const uint4* bsrc = (const uint4*)(p.w4t + (size_t)kt * 4096 + r * 32 + cb);
    const uint4 bv0 = bsrc[0], bv1 = bsrc[1];
    __syncthreads();
    *(uint4*)&At[r * LDA + cb] = av0;
    *(uint4*)&At[r * LDA + cb + 8] = av1;
    *(uint4*)&Bs[r * LDB + cb] = bv0;
    *(uint4*)&Bs[r * LDB + cb + 8] = bv1;
    __syncthreads();
    mfma_step(At, 0, Bs, acc, wm, wn, lid, q);
  }
  ln_silu(acc, lnb, p.b1, p.g1, p.bb1, wm, wn, lid, q);
  write_tile(acc, At, wm, wn, lid, q);  // t3 -> At

  // GEMM5: K=128 from At
#pragma unroll
  for (int a = 0; a < 4; ++a)
#pragma unroll
    for (int b = 0; b < 4; ++b) acc[a][b] = (f32x4){0.f, 0.f, 0.f, 0.f};
  for (int kt = 0; kt < 4; ++kt) {
    const uint4* bsrc = (const uint4*)(p.w5t + (size_t)kt * 4096 + r * 32 + cb);
    const uint4 bv0 = bsrc[0], bv1 = bsrc[1];
    __syncthreads();
    *(uint4*)&Bs[r * LDB + cb] = bv0;
    *(uint4*)&Bs[r * LDB + cb + 8] = bv1;
    __syncthreads();
    mfma_step(At, kt * 32, Bs, acc, wm, wn, lid, q);
  }

  float biasc[4];
#pragma unroll
  for (int nf = 0; nf < 4; ++nf) biasc[nf] = p.b5[wn * 64 + nf * 16 + lid];
#pragma unroll
  for (int mf = 0; mf < 4; ++mf)
#pragma unroll
    for (int rg = 0; rg < 4; ++rg) {
      const int row = wm * 64 + mf * 16 + q * 4 + rg;
      const int n = row0 + row;
      if (n < NN) {
#pragma unroll
        for (int nf = 0; nf < 4; ++nf) {
          const int c = wn * 64 + nf * 16 + lid;
          const float v = acc[mf][nf][rg] + biasc[nf] + p.hf[(size_t)n * HD + c];
          p.hf_out[(size_t)n * HD + c] = v;
          p.hb_out[(size_t)n * HD + c] = f2b(v);
        }
      }
    }
}

// ---------------- host ----------------

extern "C" void kernel_launch(void* const* d_in, const int* in_sizes, int n_in,
                              void* d_out, int out_size, void* d_ws, size_t ws_size,
                              hipStream_t stream) {
  (void)in_sizes; (void)n_in; (void)out_size; (void)ws_size;
  const float* x_in = (const float*)d_in[0];
  const float* h_in = (const float*)d_in[1];
  const int* edges = (const int*)d_in[2];
  const float* eattr = (const float*)d_in[3];
  const float* emb_w = (const float*)d_in[4];
  const float* emb_b = (const float*)d_in[5];
  const float* out_w = (const float*)d_in[6];
  const float* out_b = (const float*)d_in[7];
  const float* pe_w1 = (const float*)d_in[8];
  const float* pe_b1 = (const float*)d_in[9];
  const float* pe_g1 = (const float*)d_in[10];
  const float* pe_bb1 = (const float*)d_in[11];
  const float* pe_w2 = (const float*)d_in[12];
  const float* pe_b2 = (const float*)d_in[13];
  const float* pe_g2 = (const float*)d_in[14];
  const float* pe_bb2 = (const float*)d_in[15];
  const float* px_w1 = (const float*)d_in[16];
  const float* px_b1 = (const float*)d_in[17];
  const float* px_g1 = (const float*)d_in[18];
  const float* px_bb1 = (const float*)d_in[19];
  const float* px_w2 = (const float*)d_in[20];
  const float* px_b2 = (const float*)d_in[21];
  const float* ph_w1 = (const float*)d_in[22];
  const float* ph_b1 = (const float*)d_in[23];
  const float* ph_g1 = (const float*)d_in[24];
  const float* ph_bb1 = (const float*)d_in[25];
  const float* ph_w2 = (const float*)d_in[26];
  const float* ph_b2 = (const float*)d_in[27];
  float* out = (float*)d_out;

  char* ws = (char*)d_ws;
  size_t off = 0;
  auto alloc = [&](size_t bytes) -> void* {
    void* ptr = ws + off;
    off = (off + bytes + 255) & ~(size_t)255;
    return ptr;
  };
  float* hf = (float*)alloc((size_t)NN * HD * 4);
  unsigned short* hb = (unsigned short*)alloc((size_t)NN * HD * 2);
  float* aggh = (float*)alloc((size_t)NN * HD * 4);
  float* xf = (float*)alloc((size_t)NN * 3 * 4);
  float* cinv = (float*)alloc((size_t)NN * 4);
  float* dvec = (float*)alloc((size_t)NE * 4 * 4);
  unsigned short* e8 = (unsigned short*)alloc((size_t)NE * 8 * 2);
  unsigned short* tbuf = (unsigned short*)alloc((size_t)NE * HD * 2);
  float* sc = (float*)alloc((size_t)NE * 4);
  int* deg = (int*)alloc((size_t)NN * 4);
  int* cursor = (int*)alloc((size_t)NN * 4);
  int* rowptr = (int*)alloc((size_t)(NN + 1) * 4);
  int* eids = (int*)alloc((size_t)NE * 4);
  unsigned short* w1t = (unsigned short*)alloc((size_t)NL * 9 * 4096 * 2);
  unsigned short* w2t = (unsigned short*)alloc((size_t)NL * 4 * 4096 * 2);
  unsigned short* w3t = (unsigned short*)alloc((size_t)NL * 4 * 4096 * 2);
  unsigned short* w4t = (unsigned short*)alloc((size_t)NL * 8 * 4096 * 2);
  unsigned short* w5t = (unsigned short*)alloc((size_t)NL * 4 * 4096 * 2);

  prep_zero_k<<<(NN * 3 + 255) / 256, 256, 0, stream>>>(x_in, xf, cinv, deg);
  count_k<<<(NE + 255) / 256, 256, 0, stream>>>(edges, cinv, deg);
  inv_k<<<(NN + 255) / 256, 256, 0, stream>>>(cinv);
  scan_k<<<1, 256, 0, stream>>>(deg, rowptr, cursor);
  scatter_k<<<(NE + 255) / 256, 256, 0, stream>>>(edges, cursor, eids);
  prep_w_k<<<(NL * 9 * 4096 + 255) / 256, 256, 0, stream>>>(pe_w1, w1t, 9, 261);
  prep_w_k<<<(NL * 4 * 4096 + 255) / 256, 256, 0, stream>>>(pe_w2, w2t, 4, 128);
  prep_w_k<<<(NL * 4 * 4096 + 255) / 256, 256, 0, stream>>>(px_w1, w3t, 4, 128);
  prep_w_k<<<(NL * 8 * 4096 + 255) / 256, 256, 0, stream>>>(ph_w1, w4t, 8, 256);
  prep_w_k<<<(NL * 4 * 4096 + 255) / 256, 256, 0, stream>>>(ph_w2, w5t, 4, 128);
  emb_k<<<(NN * HD + 255) / 256, 256, 0, stream>>>(h_in, emb_w, emb_b, hf, hb);

  const int egrid = NE / 128;          // 2500
  const int ngrid = (NN + 127) / 128;  // 157

  for (int l = 0; l < NL; ++l) {
    prepd_k<<<(NE + 255) / 256, 256, 0, stream>>>(xf, edges, eattr, dvec, e8);
    {
      EP p{};
      p.hb = hb; p.e8 = e8; p.edges = edges;
      p.w1 = w1t + (size_t)l * 9 * 4096;
      p.w2 = w2t + (size_t)l * 4 * 4096;
      p.w3 = w3t + (size_t)l * 4 * 4096;
      p.b1 = pe_b1 + l * HD; p.g1 = pe_g1 + l * HD; p.bb1 = pe_bb1 + l * HD;
      p.b2 = pe_b2 + l * HD; p.g2 = pe_g2 + l * HD; p.bb2 = pe_bb2 + l * HD;
      p.b3 = px_b1 + l * HD; p.g3 = px_g1 + l * HD; p.bb3 = px_bb1 + l * HD;
      p.w4 = px_w2 + l * HD; p.b4 = px_b2 + l;
      p.tbuf = tbuf; p.sc = sc;
      edge_k<<<egrid, 256, 0, stream>>>(p);
    }
    gather_k<<<(NN + 3) / 4, 256, 0, stream>>>(tbuf, sc, dvec, rowptr, eids, cinv, aggh, xf);
    {
      NP p{};
      p.hf = hf; p.aggh = aggh;
      p.w4t = w4t + (size_t)l * 8 * 4096;
      p.w5t = w5t + (size_t)l * 4 * 4096;
      p.b1 = ph_b1 + l * HD; p.g1 = ph_g1 + l * HD; p.bb1 = ph_bb1 + l * HD;
      p.b5 = ph_b2 + l * HD;
      p.hf_out = hf; p.hb_out = hb;
      node_k<<<ngrid, 256, 0, stream>>>(p);
    }
  }

  outproj_k<<<(NN * OUTD + 255) / 256, 256, 0, stream>>>(hf, out_w, out_b, out);
  xcopy_k<<<(NN * 3 + 255) / 256, 256, 0, stream>>>(xf, out);
}

// Round 10
// 1364.991 us; speedup vs baseline: 1.8623x; 1.4264x over previous
//
#include <hip/hip_runtime.h>

#define NN 20000
#define NE 320000
#define HD 128
#define IND 16
#define OUTD 16
#define NL 4
#define LN_EPS 1e-5f
#define LDA 136  // A-tile LDS stride in shorts (272B): rows 16B-aligned for ds_read_b128

typedef __attribute__((ext_vector_type(8))) short bf16x8;
typedef __attribute__((ext_vector_type(4))) float f32x4;

__device__ __forceinline__ unsigned short f2b(float f) {
  union { float f; unsigned int u; } v; v.f = f;
  unsigned int r = v.u + 0x7FFFu + ((v.u >> 16) & 1u);
  return (unsigned short)(r >> 16);
}
__device__ __forceinline__ float b2f(unsigned int lo16) {
  union { unsigned int u; float f; } v; v.u = lo16 << 16; return v.f;
}

// ---------------- prep kernels ----------------

__global__ void prep_zero_k(const float* __restrict__ xin, float* __restrict__ xf,
                            float* __restrict__ cnt, int* __restrict__ deg) {
  int i = blockIdx.x * 256 + threadIdx.x;
  if (i < NN * 3) xf[i] = xin[i];
  if (i < NN) { cnt[i] = 0.f; deg[i] = 0; }
}

__global__ void count_k(const int* __restrict__ edges, float* __restrict__ cnt,
                        int* __restrict__ deg) {
  int e = blockIdx.x * 256 + threadIdx.x;
  if (e < NE) {
    atomicAdd(&cnt[edges[e]], 1.f);
    atomicAdd(&deg[edges[NE + e]], 1);
  }
}

__global__ void inv_k(float* __restrict__ cnt) {
  int n = blockIdx.x * 256 + threadIdx.x;
  if (n < NN) { float c = cnt[n]; cnt[n] = (c > 0.f) ? 1.f / c : 0.f; }
}

__global__ void scan_k(const int* __restrict__ deg, int* __restrict__ rowptr,
                       int* __restrict__ cursor) {
  __shared__ int part[256];
  const int tid = threadIdx.x;
  const int base = tid * 79;
  int s = 0;
  for (int t = 0; t < 79; ++t) { int idx = base + t; if (idx < NN) s += deg[idx]; }
  part[tid] = s;
  __syncthreads();
  for (int off = 1; off < 256; off <<= 1) {
    int v = (tid >= off) ? part[tid - off] : 0;
    __syncthreads();
    part[tid] += v;
    __syncthreads();
  }
  int run = (tid == 0) ? 0 : part[tid - 1];
  for (int t = 0; t < 79; ++t) {
    int idx = base + t;
    if (idx < NN) { rowptr[idx] = run; cursor[idx] = run; run += deg[idx]; }
  }
  if (tid == 255) rowptr[NN] = run;
}

__global__ void scatter_k(const int* __restrict__ edges, int* __restrict__ cursor,
                          int* __restrict__ eids) {
  int e = blockIdx.x * 256 + threadIdx.x;
  if (e < NE) {
    int d = edges[NE + e];
    int pos = atomicAdd(&cursor[d], 1);
    eids[pos] = e;
  }
}

// weights: src f32 [NL][Kreal][128] -> dst bf16 tiled [NL][KT][128][32]
__global__ void prep_w_k(const float* __restrict__ src, unsigned short* __restrict__ dst,
                         int KT, int Kreal) {
  int i = blockIdx.x * 256 + threadIdx.x;
  int total = NL * KT * 4096;
  if (i >= total) return;
  int kk = i & 31;
  int c = (i >> 5) & 127;
  int lkt = i >> 12;
  int kt = lkt % KT;
  int l = lkt / KT;
  int k = kt * 32 + kk;
  float v = (k < Kreal) ? src[((size_t)l * Kreal + k) * HD + c] : 0.f;
  dst[i] = f2b(v);
}

__global__ void emb_k(const float* __restrict__ hin, const float* __restrict__ w,
                      const float* __restrict__ b, float* __restrict__ hf,
                      unsigned short* __restrict__ hb) {
  int i = blockIdx.x * 256 + threadIdx.x;
  if (i >= NN * HD) return;
  int n = i >> 7, c = i & 127;
  float acc = b[c];
#pragma unroll
  for (int k = 0; k < IND; ++k) acc += hin[n * IND + k] * w[k * HD + c];
  hf[i] = acc;
  hb[i] = f2b(acc);
}

__global__ void prepd_k(const float* __restrict__ xf, const int* __restrict__ edges,
                        const float* __restrict__ ea, float* __restrict__ dvec,
                        unsigned short* __restrict__ e8) {
  int e = blockIdx.x * 256 + threadIdx.x;
  if (e >= NE) return;
  int j = edges[e], i = edges[NE + e];
  float dx = xf[i * 3 + 0] - xf[j * 3 + 0];
  float dy = xf[i * 3 + 1] - xf[j * 3 + 1];
  float dz = xf[i * 3 + 2] - xf[j * 3 + 2];
  float d2 = dx * dx + dy * dy + dz * dz;
  dvec[e * 4 + 0] = dx; dvec[e * 4 + 1] = dy; dvec[e * 4 + 2] = dz; dvec[e * 4 + 3] = d2;
  e8[e * 8 + 0] = f2b(d2);
#pragma unroll
  for (int a = 0; a < 4; ++a) e8[e * 8 + 1 + a] = f2b(ea[e * 4 + a]);
  e8[e * 8 + 5] = 0; e8[e * 8 + 6] = 0; e8[e * 8 + 7] = 0;
}

__global__ void outproj_k(const float* __restrict__ hf, const float* __restrict__ w,
                          const float* __restrict__ b, float* __restrict__ out) {
  int i = blockIdx.x * 256 + threadIdx.x;
  if (i >= NN * OUTD) return;
  int n = i >> 4, o = i & 15;
  float acc = b[o];
#pragma unroll 8
  for (int k = 0; k < HD; ++k) acc += hf[(size_t)n * HD + k] * w[k * OUTD + o];
  out[NN * 3 + i] = acc;
}

__global__ void xcopy_k(const float* __restrict__ xf, float* __restrict__ out) {
  int i = blockIdx.x * 256 + threadIdx.x;
  if (i < NN * 3) out[i] = xf[i];
}

// ---------------- CSR gather: agg_h + agg_x + x update ----------------

__global__ __launch_bounds__(256) void gather_k(const unsigned short* __restrict__ tbuf,
                                                const float* __restrict__ sc,
                                                const float* __restrict__ dvec,
                                                const int* __restrict__ rowptr,
                                                const int* __restrict__ eids,
                                                const float* __restrict__ cinv,
                                                float* __restrict__ aggh,
                                                float* __restrict__ xf) {
  const int n = blockIdx.x * 4 + (threadIdx.x >> 6);
  if (n >= NN) return;
  const int lane = threadIdx.x & 63;
  const int s = rowptr[n], e = rowptr[n + 1];
  float a0 = 0.f, a1 = 0.f, xa = 0.f;
  for (int t = s; t < e; ++t) {
    const int eid = eids[t];
    const unsigned int v = *(const unsigned int*)(tbuf + (size_t)eid * HD + lane * 2);
    a0 += b2f(v & 0xffffu);
    a1 += b2f(v >> 16);
    if (lane < 3) xa += dvec[(size_t)eid * 4 + lane] * sc[eid];
  }
  aggh[(size_t)n * HD + lane * 2] = a0;
  aggh[(size_t)n * HD + lane * 2 + 1] = a1;
  if (lane < 3) xf[n * 3 + lane] += xa * cinv[n];
}

// ---------------- shared GEMM pieces ----------------

__device__ __forceinline__ void mfma16(const bf16x8 (&af)[4], const bf16x8 (&bq)[4],
                                       f32x4 (&acc)[4][4]) {
#pragma unroll
  for (int mf = 0; mf < 4; ++mf)
#pragma unroll
    for (int nf = 0; nf < 4; ++nf)
      acc[mf][nf] = __builtin_amdgcn_mfma_f32_16x16x32_bf16(af[mf], bq[nf], acc[mf][nf], 0, 0, 0);
}

// bias + row-LayerNorm(128) + SiLU, in place. Contains one __syncthreads.
__device__ __forceinline__ void ln_silu(f32x4 (&acc)[4][4], float (*lnb)[128][2],
                                        const float* bias, const float* g, const float* bb,
                                        int wm, int wn, int lid, int q) {
  float biasc[4], gc[4], bbc[4];
#pragma unroll
  for (int nf = 0; nf < 4; ++nf) {
    const int c = wn * 64 + nf * 16 + lid;
    biasc[nf] = bias[c]; gc[nf] = g[c]; bbc[nf] = bb[c];
  }
#pragma unroll
  for (int mf = 0; mf < 4; ++mf)
#pragma unroll
    for (int nf = 0; nf < 4; ++nf)
#pragma unroll
      for (int rg = 0; rg < 4; ++rg) acc[mf][nf][rg] += biasc[nf];

  float s_[4][4], ss_[4][4];
#pragma unroll
  for (int mf = 0; mf < 4; ++mf)
#pragma unroll
    for (int rg = 0; rg < 4; ++rg) {
      float a = 0.f, b = 0.f;
#pragma unroll
      for (int nf = 0; nf < 4; ++nf) { float v = acc[mf][nf][rg]; a += v; b += v * v; }
      s_[mf][rg] = a; ss_[mf][rg] = b;
    }
#pragma unroll
  for (int m = 1; m < 16; m <<= 1) {
#pragma unroll
    for (int mf = 0; mf < 4; ++mf)
#pragma unroll
      for (int rg = 0; rg < 4; ++rg) {
        s_[mf][rg] += __shfl_xor(s_[mf][rg], m);
        ss_[mf][rg] += __shfl_xor(ss_[mf][rg], m);
      }
  }
  if (lid == 0) {
#pragma unroll
    for (int mf = 0; mf < 4; ++mf)
#pragma unroll
      for (int rg = 0; rg < 4; ++rg) {
        const int rl = wm * 64 + mf * 16 + q * 4 + rg;
        lnb[wn][rl][0] = s_[mf][rg];
        lnb[wn][rl][1] = ss_[mf][rg];
      }
  }
  __syncthreads();
#pragma unroll
  for (int mf = 0; mf < 4; ++mf)
#pragma unroll
    for (int rg = 0; rg < 4; ++rg) {
      const int rl = wm * 64 + mf * 16 + q * 4 + rg;
      const float t0 = lnb[0][rl][0] + lnb[1][rl][0];
      const float t1 = lnb[0][rl][1] + lnb[1][rl][1];
      const float mu = t0 * (1.f / HD);
      const float var = t1 * (1.f / HD) - mu * mu;
      const float rstd = rsqrtf(var + LN_EPS);
#pragma unroll
      for (int nf = 0; nf < 4; ++nf) {
        float v = acc[mf][nf][rg];
        v = (v - mu) * rstd * gc[nf] + bbc[nf];
        acc[mf][nf][rg] = v / (1.f + __expf(-v));
      }
    }
}

// write C fragments (bf16) into the full A-tile (row=C-row, col=C-col)
__device__ __forceinline__ void write_tile(const f32x4 (&acc)[4][4], unsigned short* At,
                                           int wm, int wn, int lid, int q) {
#pragma unroll
  for (int mf = 0; mf < 4; ++mf)
#pragma unroll
    for (int rg = 0; rg < 4; ++rg) {
      const int row = wm * 64 + mf * 16 + q * 4 + rg;
#pragma unroll
      for (int nf = 0; nf < 4; ++nf) {
        const int col = wn * 64 + nf * 16 + lid;
        At[row * LDA + col] = f2b(acc[mf][nf][rg]);
      }
    }
}

// ---------------- fused edge kernel ----------------
// GEMM1(K=288, A gathered direct from global) -> LN/SiLU -> GEMM2(A from LDS)
// -> LN/SiLU -> tbuf store -> GEMM3 -> LN/SiLU -> dot(w4) -> sc.
// B fragments loaded DIRECT from global (L2-resident weights): no barriers in K-loops.

struct EP {
  const unsigned short* hb;
  const unsigned short* e8;
  const int* edges;
  const unsigned short *w1, *w2, *w3;
  const float *b1, *g1, *bb1, *b2, *g2, *bb2, *b3, *g3, *bb3;
  const float *w4, *b4;
  unsigned short* tbuf;
  float* sc;
};

__global__ __launch_bounds__(256, 2) void edge_k(EP p) {
  __shared__ __align__(16) unsigned short At[128 * LDA];
  __shared__ float lnb[2][2][128][2];  // [phase][wn][row][{s,ss}]

  const int tid = threadIdx.x, lane = tid & 63, lid = lane & 15, q = lane >> 4;
  const int wave = tid >> 6, wm = wave >> 1, wn = wave & 1;
  const int row0 = blockIdx.x * 128;

  int rowA[4], ei[4], ej[4], colB[4];
#pragma unroll
  for (int mf = 0; mf < 4; ++mf) {
    rowA[mf] = wm * 64 + mf * 16 + lid;
    ei[mf] = p.edges[NE + row0 + rowA[mf]];
    ej[mf] = p.edges[row0 + rowA[mf]];
  }
#pragma unroll
  for (int nf = 0; nf < 4; ++nf) colB[nf] = wn * 64 + nf * 16 + lid;

  const bf16x8 zv = {0, 0, 0, 0, 0, 0, 0, 0};

  // fragment loaders (kt always a compile-time literal at call sites -> branches fold)
  auto ld1 = [&](int kt, bf16x8 (&A)[4], bf16x8 (&B)[4]) {
#pragma unroll
    for (int mf = 0; mf < 4; ++mf) {
      if (kt < 4)
        A[mf] = *(const bf16x8*)(p.hb + (size_t)ei[mf] * HD + kt * 32 + q * 8);
      else if (kt < 8)
        A[mf] = *(const bf16x8*)(p.hb + (size_t)ej[mf] * HD + (kt - 4) * 32 + q * 8);
      else if (q == 0)
        A[mf] = *(const bf16x8*)(p.e8 + (size_t)(row0 + rowA[mf]) * 8);
      else
        A[mf] = zv;
    }
#pragma unroll
    for (int nf = 0; nf < 4; ++nf)
      B[nf] = *(const bf16x8*)(p.w1 + (size_t)kt * 4096 + colB[nf] * 32 + q * 8);
  };
  auto ldL = [&](const unsigned short* wt, int kt, bf16x8 (&A)[4], bf16x8 (&B)[4]) {
#pragma unroll
    for (int mf = 0; mf < 4; ++mf)
      A[mf] = *(const bf16x8*)&At[rowA[mf] * LDA + kt * 32 + q * 8];
#pragma unroll
    for (int nf = 0; nf < 4; ++nf)
      B[nf] = *(const bf16x8*)(wt + (size_t)kt * 4096 + colB[nf] * 32 + q * 8);
  };

  f32x4 acc[4][4];
#pragma unroll
  for (int a = 0; a < 4; ++a)
#pragma unroll
    for (int b = 0; b < 4; ++b) acc[a][b] = (f32x4){0.f, 0.f, 0.f, 0.f};

  bf16x8 A0[4], B0[4], A1[4], B1[4], A2[4], B2[4];

  // GEMM1: 9 k-tiles, depth-2 register pipeline, no barriers
  ld1(0, A0, B0); ld1(1, A1, B1);
  ld1(2, A2, B2); mfma16(A0, B0, acc);
  ld1(3, A0, B0); mfma16(A1, B1, acc);
  ld1(4, A1, B1); mfma16(A2, B2, acc);
  ld1(5, A2, B2); mfma16(A0, B0, acc);
  ld1(6, A0, B0); mfma16(A1, B1, acc);
  ld1(7, A1, B1); mfma16(A2, B2, acc);
  ld1(8, A2, B2); mfma16(A0, B0, acc);
  mfma16(A1, B1, acc);
  mfma16(A2, B2, acc);

  ln_silu(acc, lnb[0], p.b1, p.g1, p.bb1, wm, wn, lid, q);
  write_tile(acc, At, wm, wn, lid, q);  // t -> At
  __syncthreads();

  // GEMM2: K=128 (A from At, B direct)
#pragma unroll
  for (int a = 0; a < 4; ++a)
#pragma unroll
    for (int b = 0; b < 4; ++b) acc[a][b] = (f32x4){0.f, 0.f, 0.f, 0.f};
  ldL(p.w2, 0, A0, B0); ldL(p.w2, 1, A1, B1);
  ldL(p.w2, 2, A2, B2); mfma16(A0, B0, acc);
  ldL(p.w2, 3, A0, B0); mfma16(A1, B1, acc);
  mfma16(A2, B2, acc);
  mfma16(A0, B0, acc);

  ln_silu(acc, lnb[1], p.b2, p.g2, p.bb2, wm, wn, lid, q);
  write_tile(acc, At, wm, wn, lid, q);  // mh -> At
  __syncthreads();

  // coalesced mh copy-out to tbuf (16B granules)
#pragma unroll
  for (int c4 = 0; c4 < 8; ++c4) {
    const int idx = tid + c4 * 256;
    const int row = idx >> 4, sl = idx & 15;
    const uint4 v = *(const uint4*)&At[row * LDA + sl * 8];
    *(uint4*)(p.tbuf + (size_t)(row0 + row) * HD + sl * 8) = v;
  }

  // GEMM3: K=128
#pragma unroll
  for (int a = 0; a < 4; ++a)
#pragma unroll
    for (int b = 0; b < 4; ++b) acc[a][b] = (f32x4){0.f, 0.f, 0.f, 0.f};
  ldL(p.w3, 0, A0, B0); ldL(p.w3, 1, A1, B1);
  ldL(p.w3, 2, A2, B2); mfma16(A0, B0, acc);
  ldL(p.w3, 3, A0, B0); mfma16(A1, B1, acc);
  mfma16(A2, B2, acc);
  mfma16(A0, B0, acc);

  ln_silu(acc, lnb[0], p.b3, p.g3, p.bb3, wm, wn, lid, q);

  // per-edge scalar: sc = dot(t2_row, w4) + b4 (uses lnb[1] slot; safe: last
  // lnb[1] reads completed before the post-write_tile(mh) barrier)
  float w4c[4];
#pragma unroll
  for (int nf = 0; nf < 4; ++nf) w4c[nf] = p.w4[colB[nf]];
  float dp[4][4];
#pragma unroll
  for (int mf = 0; mf < 4; ++mf)
#pragma unroll
    for (int rg = 0; rg < 4; ++rg) {
      float a = 0.f;
#pragma unroll
      for (int nf = 0; nf < 4; ++nf) a += acc[mf][nf][rg] * w4c[nf];
      dp[mf][rg] = a;
    }
#pragma unroll
  for (int m = 1; m < 16; m <<= 1) {
#pragma unroll
    for (int mf = 0; mf < 4; ++mf)
#pragma unroll
      for (int rg = 0; rg < 4; ++rg) dp[mf][rg] += __shfl_xor(dp[mf][rg], m);
  }
  if (lid == 0) {
#pragma unroll
    for (int mf = 0; mf < 4; ++mf)
#pragma unroll
      for (int rg = 0; rg < 4; ++rg)
        lnb[1][wn][wm * 64 + mf * 16 + q * 4 + rg][0] = dp[mf][rg];
  }
  __syncthreads();
  if (tid < 128) p.sc[row0 + tid] = lnb[1][0][tid][0] + lnb[1][1][tid][0] + p.b4[0];
}

// ---------------- fused node kernel: GEMM4 -> LN/SiLU -> GEMM5 -> +bias+resid ----------------

struct NP {
  const float* hf;
  const float* aggh;
  const unsigned short *w4t, *w5t;
  const float *b1, *g1, *bb1, *b5;
  float* hf_out;
  unsigned short* hb_out;
};

__global__ __launch_bounds__(256, 2) void node_k(NP p) {
  __shared__ __align__(16) unsigned short At[128 * LDA];
  __shared__ float lnb[1][2][128][2];

  const int tid = threadIdx.x, lane = tid & 63, lid = lane & 15, q = lane >> 4;
  const int wave = tid >> 6, wm = wave >> 1, wn = wave & 1;
  const int row0 = blockIdx.x * 128;

  int rowA[4], nrow[4], colB[4];
  bool okm[4];
#pragma unroll
  for (int mf = 0; mf < 4; ++mf) {
    rowA[mf] = wm * 64 + mf * 16 + lid;
    nrow[mf] = row0 + rowA[mf];
    okm[mf] = nrow[mf] < NN;
  }
#pragma unroll
  for (int nf = 0; nf < 4; ++nf) colB[nf] = wn * 64 + nf * 16 + lid;

  const bf16x8 zv = {0, 0, 0, 0, 0, 0, 0, 0};

  auto ld4 = [&](int kt, bf16x8 (&A)[4], bf16x8 (&B)[4]) {
#pragma unroll
    for (int mf = 0; mf < 4; ++mf) {
      if (!okm[mf]) { A[mf] = zv; continue; }
      const float* s = (kt < 4) ? (p.hf + (size_t)nrow[mf] * HD + kt * 32 + q * 8)
                                : (p.aggh + (size_t)nrow[mf] * HD + (kt - 4) * 32 + q * 8);
      const float4 f0 = *(const float4*)s;
      const float4 f1 = *(const float4*)(s + 4);
      unsigned short t[8];
      t[0] = f2b(f0.x); t[1] = f2b(f0.y); t[2] = f2b(f0.z); t[3] = f2b(f0.w);
      t[4] = f2b(f1.x); t[5] = f2b(f1.y); t[6] = f2b(f1.z); t[7] = f2b(f1.w);
      A[mf] = *(const bf16x8*)t;
    }
#pragma unroll
    for (int nf = 0; nf < 4; ++nf)
      B[nf] = *(const bf16x8*)(p.w4t + (size_t)kt * 4096 + colB[nf] * 32 + q * 8);
  };
  auto ld5 = [&](int kt, bf16x8 (&A)[4], bf16x8 (&B)[4]) {
#pragma unroll
    for (int mf = 0; mf < 4; ++mf)
      A[mf] = *(const bf16x8*)&At[rowA[mf] * LDA + kt * 32 + q * 8];
#pragma unroll
    for (int nf = 0; nf < 4; ++nf)
      B[nf] = *(const bf16x8*)(p.w5t + (size_t)kt * 4096 + colB[nf] * 32 + q * 8);
  };

  f32x4 acc[4][4];
#pragma unroll
  for (int a = 0; a < 4; ++a)
#pragma unroll
    for (int b = 0; b < 4; ++b) acc[a][b] = (f32x4){0.f, 0.f, 0.f, 0.f};

  bf16x8 A0[4], B0[4], A1[4], B1[4], A2[4], B2[4];

  // GEMM4: K=256 ([h | agg_h] converted on the fly), depth-2 pipeline.
  // 8 k-tiles -> exactly 8 MFMA groups (round-9 bug: kt5 was consumed twice).
  ld4(0, A0, B0); ld4(1, A1, B1);
  ld4(2, A2, B2); mfma16(A0, B0, acc);  // kt0
  ld4(3, A0, B0); mfma16(A1, B1, acc);  // kt1
  ld4(4, A1, B1); mfma16(A2, B2, acc);  // kt2
  ld4(5, A2, B2); mfma16(A0, B0, acc);  // kt3
  ld4(6, A0, B0); mfma16(A1, B1, acc);  // kt4
  ld4(7, A1, B1); mfma16(A2, B2, acc);  // kt5
  mfma16(A0, B0, acc);                  // kt6
  mfma16(A1, B1, acc);                  // kt7

  ln_silu(acc, lnb[0], p.b1, p.g1, p.bb1, wm, wn, lid, q);
  write_tile(acc, At, wm, wn, lid, q);  // t3 -> At
  __syncthreads();

  // GEMM5: K=128
#pragma unroll
  for (int a = 0; a < 4; ++a)
#pragma unroll
    for (int b = 0; b < 4; ++b) acc[a][b] = (f32x4){0.f, 0.f, 0.f, 0.f};
  ld5(0, A0, B0); ld5(1, A1, B1);
  ld5(2, A2, B2); mfma16(A0, B0, acc);
  ld5(3, A0, B0); mfma16(A1, B1, acc);
  mfma16(A2, B2, acc);
  mfma16(A0, B0, acc);

  float biasc[4];
#pragma unroll
  for (int nf = 0; nf < 4; ++nf) biasc[nf] = p.b5[colB[nf]];
#pragma unroll
  for (int mf = 0; mf < 4; ++mf)
#pragma unroll
    for (int rg = 0; rg < 4; ++rg) {
      const int row = wm * 64 + mf * 16 + q * 4 + rg;
      const int n = row0 + row;
      if (n < NN) {
#pragma unroll
        for (int nf = 0; nf < 4; ++nf) {
          const int c = colB[nf];
          const float v = acc[mf][nf][rg] + biasc[nf] + p.hf[(size_t)n * HD + c];
          p.hf_out[(size_t)n * HD + c] = v;
          p.hb_out[(size_t)n * HD + c] = f2b(v);
        }
      }
    }
}

// ---------------- host ----------------

extern "C" void kernel_launch(void* const* d_in, const int* in_sizes, int n_in,
                              void* d_out, int out_size, void* d_ws, size_t ws_size,
                              hipStream_t stream) {
  (void)in_sizes; (void)n_in; (void)out_size; (void)ws_size;
  const float* x_in = (const float*)d_in[0];
  const float* h_in = (const float*)d_in[1];
  const int* edges = (const int*)d_in[2];
  const float* eattr = (const float*)d_in[3];
  const float* emb_w = (const float*)d_in[4];
  const float* emb_b = (const float*)d_in[5];
  const float* out_w = (const float*)d_in[6];
  const float* out_b = (const float*)d_in[7];
  const float* pe_w1 = (const float*)d_in[8];
  const float* pe_b1 = (const float*)d_in[9];
  const float* pe_g1 = (const float*)d_in[10];
  const float* pe_bb1 = (const float*)d_in[11];
  const float* pe_w2 = (const float*)d_in[12];
  const float* pe_b2 = (const float*)d_in[13];
  const float* pe_g2 = (const float*)d_in[14];
  const float* pe_bb2 = (const float*)d_in[15];
  const float* px_w1 = (const float*)d_in[16];
  const float* px_b1 = (const float*)d_in[17];
  const float* px_g1 = (const float*)d_in[18];
  const float* px_bb1 = (const float*)d_in[19];
  const float* px_w2 = (const float*)d_in[20];
  const float* px_b2 = (const float*)d_in[21];
  const float* ph_w1 = (const float*)d_in[22];
  const float* ph_b1 = (const float*)d_in[23];
  const float* ph_g1 = (const float*)d_in[24];
  const float* ph_bb1 = (const float*)d_in[25];
  const float* ph_w2 = (const float*)d_in[26];
  const float* ph_b2 = (const float*)d_in[27];
  float* out = (float*)d_out;

  char* ws = (char*)d_ws;
  size_t off = 0;
  auto alloc = [&](size_t bytes) -> void* {
    void* ptr = ws + off;
    off = (off + bytes + 255) & ~(size_t)255;
    return ptr;
  };
  float* hf = (float*)alloc((size_t)NN * HD * 4);
  unsigned short* hb = (unsigned short*)alloc((size_t)NN * HD * 2);
  float* aggh = (float*)alloc((size_t)NN * HD * 4);
  float* xf = (float*)alloc((size_t)NN * 3 * 4);
  float* cinv = (float*)alloc((size_t)NN * 4);
  float* dvec = (float*)alloc((size_t)NE * 4 * 4);
  unsigned short* e8 = (unsigned short*)alloc((size_t)NE * 8 * 2);
  unsigned short* tbuf = (unsigned short*)alloc((size_t)NE * HD * 2);
  float* sc = (float*)alloc((size_t)NE * 4);
  int* deg = (int*)alloc((size_t)NN * 4);
  int* cursor = (int*)alloc((size_t)NN * 4);
  int* rowptr = (int*)alloc((size_t)(NN + 1) * 4);
  int* eids = (int*)alloc((size_t)NE * 4);
  unsigned short* w1t = (unsigned short*)alloc((size_t)NL * 9 * 4096 * 2);
  unsigned short* w2t = (unsigned short*)alloc((size_t)NL * 4 * 4096 * 2);
  unsigned short* w3t = (unsigned short*)alloc((size_t)NL * 4 * 4096 * 2);
  unsigned short* w4t = (unsigned short*)alloc((size_t)NL * 8 * 4096 * 2);
  unsigned short* w5t = (unsigned short*)alloc((size_t)NL * 4 * 4096 * 2);

  prep_zero_k<<<(NN * 3 + 255) / 256, 256, 0, stream>>>(x_in, xf, cinv, deg);
  count_k<<<(NE + 255) / 256, 256, 0, stream>>>(edges, cinv, deg);
  inv_k<<<(NN + 255) / 256, 256, 0, stream>>>(cinv);
  scan_k<<<1, 256, 0, stream>>>(deg, rowptr, cursor);
  scatter_k<<<(NE + 255) / 256, 256, 0, stream>>>(edges, cursor, eids);
  prep_w_k<<<(NL * 9 * 4096 + 255) / 256, 256, 0, stream>>>(pe_w1, w1t, 9, 261);
  prep_w_k<<<(NL * 4 * 4096 + 255) / 256, 256, 0, stream>>>(pe_w2, w2t, 4, 128);
  prep_w_k<<<(NL * 4 * 4096 + 255) / 256, 256, 0, stream>>>(px_w1, w3t, 4, 128);
  prep_w_k<<<(NL * 8 * 4096 + 255) / 256, 256, 0, stream>>>(ph_w1, w4t, 8, 256);
  prep_w_k<<<(NL * 4 * 4096 + 255) / 256, 256, 0, stream>>>(ph_w2, w5t, 4, 128);
  emb_k<<<(NN * HD + 255) / 256, 256, 0, stream>>>(h_in, emb_w, emb_b, hf, hb);

  const int egrid = NE / 128;          // 2500
  const int ngrid = (NN + 127) / 128;  // 157

  for (int l = 0; l < NL; ++l) {
    prepd_k<<<(NE + 255) / 256, 256, 0, stream>>>(xf, edges, eattr, dvec, e8);
    {
      EP p{};
      p.hb = hb; p.e8 = e8; p.edges = edges;
      p.w1 = w1t + (size_t)l * 9 * 4096;
      p.w2 = w2t + (size_t)l * 4 * 4096;
      p.w3 = w3t + (size_t)l * 4 * 4096;
      p.b1 = pe_b1 + l * HD; p.g1 = pe_g1 + l * HD; p.bb1 = pe_bb1 + l * HD;
      p.b2 = pe_b2 + l * HD; p.g2 = pe_g2 + l * HD; p.bb2 = pe_bb2 + l * HD;
      p.b3 = px_b1 + l * HD; p.g3 = px_g1 + l * HD; p.bb3 = px_bb1 + l * HD;
      p.w4 = px_w2 + l * HD; p.b4 = px_b2 + l;
      p.tbuf = tbuf; p.sc = sc;
      edge_k<<<egrid, 256, 0, stream>>>(p);
    }
    gather_k<<<(NN + 3) / 4, 256, 0, stream>>>(tbuf, sc, dvec, rowptr, eids, cinv, aggh, xf);
    {
      NP p{};
      p.hf = hf; p.aggh = aggh;
      p.w4t = w4t + (size_t)l * 8 * 4096;
      p.w5t = w5t + (size_t)l * 4 * 4096;
      p.b1 = ph_b1 + l * HD; p.g1 = ph_g1 + l * HD; p.bb1 = ph_bb1 + l * HD;
      p.b5 = ph_b2 + l * HD;
      p.hf_out = hf; p.hb_out = hb;
      node_k<<<ngrid, 256, 0, stream>>>(p);
    }
  }

  outproj_k<<<(NN * OUTD + 255) / 256, 256, 0, stream>>>(hf, out_w, out_b, out);
  xcopy_k<<<(NN * 3 + 255) / 256, 256, 0, stream>>>(xf, out);
}

// Round 11
// 1215.025 us; speedup vs baseline: 2.0922x; 1.1234x over previous
//
#include <hip/hip_runtime.h>
#include <hip/hip_bf16.h>

#define NN 20000
#define NE 320000
#define HD 128
#define IND 16
#define OUTD 16
#define NL 4
#define LN_EPS 1e-5f
#define LDA 136  // LDS row stride in shorts (272B): 16B-aligned rows, ~2-way banks

typedef __attribute__((ext_vector_type(8))) short bf16x8;
typedef __attribute__((ext_vector_type(4))) float f32x4;

__device__ __forceinline__ unsigned short f2b(float f) {
  __hip_bfloat16 h = __float2bfloat16(f);  // RNE; compiler packs v_cvt_pk_bf16_f32
  unsigned short u;
  __builtin_memcpy(&u, &h, 2);
  return u;
}
__device__ __forceinline__ float b2f(unsigned int lo16) {
  union { unsigned int u; float f; } v; v.u = lo16 << 16; return v.f;
}

// ---------------- prep kernels ----------------

__global__ void prep_zero_k(const float* __restrict__ xin, float* __restrict__ xf,
                            float* __restrict__ cnt, int* __restrict__ deg) {
  int i = blockIdx.x * 256 + threadIdx.x;
  if (i < NN * 3) xf[i] = xin[i];
  if (i < NN) { cnt[i] = 0.f; deg[i] = 0; }
}

__global__ void count_k(const int* __restrict__ edges, float* __restrict__ cnt,
                        int* __restrict__ deg) {
  int e = blockIdx.x * 256 + threadIdx.x;
  if (e < NE) {
    atomicAdd(&cnt[edges[e]], 1.f);
    atomicAdd(&deg[edges[NE + e]], 1);
  }
}

__global__ void inv_k(float* __restrict__ cnt) {
  int n = blockIdx.x * 256 + threadIdx.x;
  if (n < NN) { float c = cnt[n]; cnt[n] = (c > 0.f) ? 1.f / c : 0.f; }
}

__global__ void scan_k(const int* __restrict__ deg, int* __restrict__ rowptr,
                       int* __restrict__ cursor) {
  __shared__ int part[256];
  const int tid = threadIdx.x;
  const int base = tid * 79;
  int s = 0;
  for (int t = 0; t < 79; ++t) { int idx = base + t; if (idx < NN) s += deg[idx]; }
  part[tid] = s;
  __syncthreads();
  for (int off = 1; off < 256; off <<= 1) {
    int v = (tid >= off) ? part[tid - off] : 0;
    __syncthreads();
    part[tid] += v;
    __syncthreads();
  }
  int run = (tid == 0) ? 0 : part[tid - 1];
  for (int t = 0; t < 79; ++t) {
    int idx = base + t;
    if (idx < NN) { rowptr[idx] = run; cursor[idx] = run; run += deg[idx]; }
  }
  if (tid == 255) rowptr[NN] = run;
}

__global__ void scatter_k(const int* __restrict__ edges, int* __restrict__ cursor,
                          int* __restrict__ eids) {
  int e = blockIdx.x * 256 + threadIdx.x;
  if (e < NE) {
    int d = edges[NE + e];
    int pos = atomicAdd(&cursor[d], 1);
    eids[pos] = e;
  }
}

// weights: src f32 [NL][Kreal][128] -> dst bf16 tiled [NL][KT][128][32]
__global__ void prep_w_k(const float* __restrict__ src, unsigned short* __restrict__ dst,
                         int KT, int Kreal) {
  int i = blockIdx.x * 256 + threadIdx.x;
  int total = NL * KT * 4096;
  if (i >= total) return;
  int kk = i & 31;
  int c = (i >> 5) & 127;
  int lkt = i >> 12;
  int kt = lkt % KT;
  int l = lkt / KT;
  int k = kt * 32 + kk;
  float v = (k < Kreal) ? src[((size_t)l * Kreal + k) * HD + c] : 0.f;
  dst[i] = f2b(v);
}

__global__ void emb_k(const float* __restrict__ hin, const float* __restrict__ w,
                      const float* __restrict__ b, float* __restrict__ hf,
                      unsigned short* __restrict__ hb) {
  int i = blockIdx.x * 256 + threadIdx.x;
  if (i >= NN * HD) return;
  int n = i >> 7, c = i & 127;
  float acc = b[c];
#pragma unroll
  for (int k = 0; k < IND; ++k) acc += hin[n * IND + k] * w[k * HD + c];
  hf[i] = acc;
  hb[i] = f2b(acc);
}

__global__ void prepd_k(const float* __restrict__ xf, const int* __restrict__ edges,
                        const float* __restrict__ ea, float* __restrict__ dvec,
                        unsigned short* __restrict__ e8) {
  int e = blockIdx.x * 256 + threadIdx.x;
  if (e >= NE) return;
  int j = edges[e], i = edges[NE + e];
  float dx = xf[i * 3 + 0] - xf[j * 3 + 0];
  float dy = xf[i * 3 + 1] - xf[j * 3 + 1];
  float dz = xf[i * 3 + 2] - xf[j * 3 + 2];
  float d2 = dx * dx + dy * dy + dz * dz;
  dvec[e * 4 + 0] = dx; dvec[e * 4 + 1] = dy; dvec[e * 4 + 2] = dz; dvec[e * 4 + 3] = d2;
  e8[e * 8 + 0] = f2b(d2);
#pragma unroll
  for (int a = 0; a < 4; ++a) e8[e * 8 + 1 + a] = f2b(ea[e * 4 + a]);
  e8[e * 8 + 5] = 0; e8[e * 8 + 6] = 0; e8[e * 8 + 7] = 0;
}

__global__ void outproj_k(const float* __restrict__ hf, const float* __restrict__ w,
                          const float* __restrict__ b, float* __restrict__ out) {
  int i = blockIdx.x * 256 + threadIdx.x;
  if (i >= NN * OUTD) return;
  int n = i >> 4, o = i & 15;
  float acc = b[o];
#pragma unroll 8
  for (int k = 0; k < HD; ++k) acc += hf[(size_t)n * HD + k] * w[k * OUTD + o];
  out[NN * 3 + i] = acc;
}

__global__ void xcopy_k(const float* __restrict__ xf, float* __restrict__ out) {
  int i = blockIdx.x * 256 + threadIdx.x;
  if (i < NN * 3) out[i] = xf[i];
}

// ---------------- CSR gather: agg_h + agg_x + x update ----------------

__global__ __launch_bounds__(256) void gather_k(const unsigned short* __restrict__ tbuf,
                                                const float* __restrict__ sc,
                                                const float* __restrict__ dvec,
                                                const int* __restrict__ rowptr,
                                                const int* __restrict__ eids,
                                                const float* __restrict__ cinv,
                                                float* __restrict__ aggh,
                                                float* __restrict__ xf) {
  const int n = blockIdx.x * 4 + (threadIdx.x >> 6);
  if (n >= NN) return;
  const int lane = threadIdx.x & 63;
  const int s = rowptr[n], e = rowptr[n + 1];
  float a0 = 0.f, a1 = 0.f, xa = 0.f;
  for (int t = s; t < e; ++t) {
    const int eid = eids[t];
    const unsigned int v = *(const unsigned int*)(tbuf + (size_t)eid * HD + lane * 2);
    a0 += b2f(v & 0xffffu);
    a1 += b2f(v >> 16);
    if (lane < 3) xa += dvec[(size_t)eid * 4 + lane] * sc[eid];
  }
  aggh[(size_t)n * HD + lane * 2] = a0;
  aggh[(size_t)n * HD + lane * 2 + 1] = a1;
  if (lane < 3) xf[n * 3 + lane] += xa * cinv[n];
}

// ---------------- wave-strip GEMM pieces (wave owns 32 rows x 128 cols) ----------------

__device__ __forceinline__ void mfma_w(const bf16x8 (&A)[2], const bf16x8 (&B)[8],
                                       f32x4 (&acc)[2][8]) {
#pragma unroll
  for (int mf = 0; mf < 2; ++mf)
#pragma unroll
    for (int nf = 0; nf < 8; ++nf)
      acc[mf][nf] = __builtin_amdgcn_mfma_f32_16x16x32_bf16(A[mf], B[nf], acc[mf][nf], 0, 0, 0);
}

#define ZACC()                                          \
  _Pragma("unroll") for (int a_ = 0; a_ < 2; ++a_)      \
  _Pragma("unroll") for (int b_ = 0; b_ < 8; ++b_)      \
      acc[a_][b_] = (f32x4){0.f, 0.f, 0.f, 0.f}

// depth-1-prefetch double-buffered K pipeline; audited: kt consumed exactly once,
// load for kt+1 lands in the buffer whose previous content was consumed at kt-1.
#define GEMM_PIPE(NKT, LD)                              \
  LD(0, A0, B0);                                        \
  _Pragma("unroll") for (int kt = 0; kt < (NKT); ++kt) {\
    if ((kt & 1) == 0) {                                \
      if (kt + 1 < (NKT)) LD(kt + 1, A1, B1);           \
      mfma_w(A0, B0, acc);                              \
    } else {                                            \
      if (kt + 1 < (NKT)) LD(kt + 1, A0, B0);           \
      mfma_w(A1, B1, acc);                              \
    }                                                   \
  }

// bias + row-LayerNorm(128) + SiLU, fully wave-local (no LDS, no barrier).
__device__ __forceinline__ void ln_silu_w(f32x4 (&acc)[2][8], const float* bias,
                                          const float* g, const float* bb, int lid) {
  float biasc[8], gc[8], bbc[8];
#pragma unroll
  for (int nf = 0; nf < 8; ++nf) {
    const int c = nf * 16 + lid;
    biasc[nf] = bias[c]; gc[nf] = g[c]; bbc[nf] = bb[c];
  }
#pragma unroll
  for (int mf = 0; mf < 2; ++mf)
#pragma unroll
    for (int nf = 0; nf < 8; ++nf)
#pragma unroll
      for (int rg = 0; rg < 4; ++rg) acc[mf][nf][rg] += biasc[nf];

  float s_[2][4], ss_[2][4];
#pragma unroll
  for (int mf = 0; mf < 2; ++mf)
#pragma unroll
    for (int rg = 0; rg < 4; ++rg) {
      float a = 0.f, b = 0.f;
#pragma unroll
      for (int nf = 0; nf < 8; ++nf) { float v = acc[mf][nf][rg]; a += v; b += v * v; }
      s_[mf][rg] = a; ss_[mf][rg] = b;
    }
#pragma unroll
  for (int m = 1; m < 16; m <<= 1) {
#pragma unroll
    for (int mf = 0; mf < 2; ++mf)
#pragma unroll
      for (int rg = 0; rg < 4; ++rg) {
        s_[mf][rg] += __shfl_xor(s_[mf][rg], m);
        ss_[mf][rg] += __shfl_xor(ss_[mf][rg], m);
      }
  }
#pragma unroll
  for (int mf = 0; mf < 2; ++mf)
#pragma unroll
    for (int rg = 0; rg < 4; ++rg) {
      const float mu = s_[mf][rg] * (1.f / HD);
      const float var = ss_[mf][rg] * (1.f / HD) - mu * mu;
      const float rstd = rsqrtf(var + LN_EPS);
#pragma unroll
      for (int nf = 0; nf < 8; ++nf) {
        float v = acc[mf][nf][rg];
        v = (v - mu) * rstd * gc[nf] + bbc[nf];
        acc[mf][nf][rg] = v / (1.f + __expf(-v));
      }
    }
}

// write this wave's 32x128 C strip (bf16) into its private LDS rows
__device__ __forceinline__ void write_strip(const f32x4 (&acc)[2][8], unsigned short* At,
                                            int rbase, int lid, int q) {
#pragma unroll
  for (int mf = 0; mf < 2; ++mf)
#pragma unroll
    for (int rg = 0; rg < 4; ++rg) {
      const int row = rbase + mf * 16 + q * 4 + rg;
#pragma unroll
      for (int nf = 0; nf < 8; ++nf)
        At[row * LDA + nf * 16 + lid] = f2b(acc[mf][nf][rg]);
    }
}

// ---------------- fused edge kernel (ZERO barriers) ----------------
// GEMM1(K=288, gathered) -> LN/SiLU -> GEMM2 -> LN/SiLU -> tbuf -> GEMM3 -> LN/SiLU
// -> dot(w4) -> sc.  Wave-private LDS strip; B direct from global (L2-resident).

struct EP {
  const unsigned short* hb;
  const unsigned short* e8;
  const int* edges;
  const unsigned short *w1, *w2, *w3;
  const float *b1, *g1, *bb1, *b2, *g2, *bb2, *b3, *g3, *bb3;
  const float *w4, *b4;
  unsigned short* tbuf;
  float* sc;
};

__global__ __launch_bounds__(256, 2) void edge_k(EP p) {
  __shared__ __align__(16) unsigned short At[128 * LDA];

  const int tid = threadIdx.x, lane = tid & 63, lid = lane & 15, q = lane >> 4;
  const int wave = tid >> 6;
  const int rbase = wave * 32;
  const int row0 = blockIdx.x * 128;

  int ei[2], ej[2];
#pragma unroll
  for (int mf = 0; mf < 2; ++mf) {
    const int r = row0 + rbase + mf * 16 + lid;
    ei[mf] = p.edges[NE + r];
    ej[mf] = p.edges[r];
  }

  const bf16x8 zv = {0, 0, 0, 0, 0, 0, 0, 0};

  auto LD1 = [&](int kt, bf16x8 (&A)[2], bf16x8 (&B)[8]) {
#pragma unroll
    for (int mf = 0; mf < 2; ++mf) {
      if (kt < 4)
        A[mf] = *(const bf16x8*)(p.hb + (size_t)ei[mf] * HD + kt * 32 + q * 8);
      else if (kt < 8)
        A[mf] = *(const bf16x8*)(p.hb + (size_t)ej[mf] * HD + (kt - 4) * 32 + q * 8);
      else if (q == 0)
        A[mf] = *(const bf16x8*)(p.e8 + (size_t)(row0 + rbase + mf * 16 + lid) * 8);
      else
        A[mf] = zv;
    }
#pragma unroll
    for (int nf = 0; nf < 8; ++nf)
      B[nf] = *(const bf16x8*)(p.w1 + (size_t)kt * 4096 + (nf * 16 + lid) * 32 + q * 8);
  };
  auto LDW = [&](const unsigned short* wt, int kt, bf16x8 (&A)[2], bf16x8 (&B)[8]) {
#pragma unroll
    for (int mf = 0; mf < 2; ++mf)
      A[mf] = *(const bf16x8*)&At[(rbase + mf * 16 + lid) * LDA + kt * 32 + q * 8];
#pragma unroll
    for (int nf = 0; nf < 8; ++nf)
      B[nf] = *(const bf16x8*)(wt + (size_t)kt * 4096 + (nf * 16 + lid) * 32 + q * 8);
  };
  auto LD2 = [&](int kt, bf16x8 (&A)[2], bf16x8 (&B)[8]) { LDW(p.w2, kt, A, B); };
  auto LD3 = [&](int kt, bf16x8 (&A)[2], bf16x8 (&B)[8]) { LDW(p.w3, kt, A, B); };

  f32x4 acc[2][8];
  bf16x8 A0[2], B0[8], A1[2], B1[8];

  // GEMM1: K=288 (9 k-tiles)
  ZACC();
  GEMM_PIPE(9, LD1);
  ln_silu_w(acc, p.b1, p.g1, p.bb1, lid);
  write_strip(acc, At, rbase, lid, q);  // t -> wave-private LDS rows

  // GEMM2: K=128
  ZACC();
  GEMM_PIPE(4, LD2);
  ln_silu_w(acc, p.b2, p.g2, p.bb2, lid);
  write_strip(acc, At, rbase, lid, q);  // mh -> LDS (compiler orders via lgkmcnt)

  // mh copy-out: wave copies its own 32 rows (16B granules, coalesced)
#pragma unroll
  for (int it = 0; it < 8; ++it) {
    const int idx = it * 64 + lane;
    const int row = idx >> 4, sl = idx & 15;
    const uint4 v = *(const uint4*)&At[(rbase + row) * LDA + sl * 8];
    *(uint4*)(p.tbuf + (size_t)(row0 + rbase + row) * HD + sl * 8) = v;
  }

  // GEMM3: K=128
  ZACC();
  GEMM_PIPE(4, LD3);
  ln_silu_w(acc, p.b3, p.g3, p.bb3, lid);

  // sc = dot(t2_row, w4) + b4 — wave-local reduce, direct store
  float w4c[8];
#pragma unroll
  for (int nf = 0; nf < 8; ++nf) w4c[nf] = p.w4[nf * 16 + lid];
  float dp[2][4];
#pragma unroll
  for (int mf = 0; mf < 2; ++mf)
#pragma unroll
    for (int rg = 0; rg < 4; ++rg) {
      float a = 0.f;
#pragma unroll
      for (int nf = 0; nf < 8; ++nf) a += acc[mf][nf][rg] * w4c[nf];
      dp[mf][rg] = a;
    }
#pragma unroll
  for (int m = 1; m < 16; m <<= 1) {
#pragma unroll
    for (int mf = 0; mf < 2; ++mf)
#pragma unroll
      for (int rg = 0; rg < 4; ++rg) dp[mf][rg] += __shfl_xor(dp[mf][rg], m);
  }
  if (lid == 0) {
    const float b4 = p.b4[0];
#pragma unroll
    for (int mf = 0; mf < 2; ++mf)
#pragma unroll
      for (int rg = 0; rg < 4; ++rg)
        p.sc[row0 + rbase + mf * 16 + q * 4 + rg] = dp[mf][rg] + b4;
  }
}

// ---------------- fused node kernel (ZERO barriers, 64-row blocks) ----------------

struct NP {
  const float* hf;
  const float* aggh;
  const unsigned short *w4t, *w5t;
  const float *b1, *g1, *bb1, *b5;
  float* hf_out;
  unsigned short* hb_out;
};

__global__ __launch_bounds__(128, 2) void node_k(NP p) {
  __shared__ __align__(16) unsigned short At[64 * LDA];

  const int tid = threadIdx.x, lane = tid & 63, lid = lane & 15, q = lane >> 4;
  const int wave = tid >> 6;  // 0..1
  const int rbase = wave * 32;
  const int row0 = blockIdx.x * 64;

  int nrow[2];
  bool okm[2];
#pragma unroll
  for (int mf = 0; mf < 2; ++mf) {
    nrow[mf] = row0 + rbase + mf * 16 + lid;
    okm[mf] = nrow[mf] < NN;
  }

  const bf16x8 zv = {0, 0, 0, 0, 0, 0, 0, 0};

  auto LD4 = [&](int kt, bf16x8 (&A)[2], bf16x8 (&B)[8]) {
#pragma unroll
    for (int mf = 0; mf < 2; ++mf) {
      if (!okm[mf]) { A[mf] = zv; continue; }
      const float* s = (kt < 4) ? (p.hf + (size_t)nrow[mf] * HD + kt * 32 + q * 8)
                                : (p.aggh + (size_t)nrow[mf] * HD + (kt - 4) * 32 + q * 8);
      const float4 f0 = *(const float4*)s;
      const float4 f1 = *(const float4*)(s + 4);
      unsigned short t[8];
      t[0] = f2b(f0.x); t[1] = f2b(f0.y); t[2] = f2b(f0.z); t[3] = f2b(f0.w);
      t[4] = f2b(f1.x); t[5] = f2b(f1.y); t[6] = f2b(f1.z); t[7] = f2b(f1.w);
      A[mf] = *(const bf16x8*)t;
    }
#pragma unroll
    for (int nf = 0; nf < 8; ++nf)
      B[nf] = *(const bf16x8*)(p.w4t + (size_t)kt * 4096 + (nf * 16 + lid) * 32 + q * 8);
  };
  auto LD5 = [&](int kt, bf16x8 (&A)[2], bf16x8 (&B)[8]) {
#pragma unroll
    for (int mf = 0; mf < 2; ++mf)
      A[mf] = *(const bf16x8*)&At[(rbase + mf * 16 + lid) * LDA + kt * 32 + q * 8];
#pragma unroll
    for (int nf = 0; nf < 8; ++nf)
      B[nf] = *(const bf16x8*)(p.w5t + (size_t)kt * 4096 + (nf * 16 + lid) * 32 + q * 8);
  };

  f32x4 acc[2][8];
  bf16x8 A0[2], B0[8], A1[2], B1[8];

  // GEMM4: K=256 (8 k-tiles)
  ZACC();
  GEMM_PIPE(8, LD4);
  ln_silu_w(acc, p.b1, p.g1, p.bb1, lid);
  write_strip(acc, At, rbase, lid, q);  // t3 -> wave-private LDS

  // GEMM5: K=128
  ZACC();
  GEMM_PIPE(4, LD5);

  float biasc[8];
#pragma unroll
  for (int nf = 0; nf < 8; ++nf) biasc[nf] = p.b5[nf * 16 + lid];
#pragma unroll
  for (int mf = 0; mf < 2; ++mf)
#pragma unroll
    for (int rg = 0; rg < 4; ++rg) {
      const int n = row0 + rbase + mf * 16 + q * 4 + rg;
      if (n < NN) {
#pragma unroll
        for (int nf = 0; nf < 8; ++nf) {
          const int c = nf * 16 + lid;
          const float v = acc[mf][nf][rg] + biasc[nf] + p.hf[(size_t)n * HD + c];
          p.hf_out[(size_t)n * HD + c] = v;
          p.hb_out[(size_t)n * HD + c] = f2b(v);
        }
      }
    }
}

// ---------------- host ----------------

extern "C" void kernel_launch(void* const* d_in, const int* in_sizes, int n_in,
                              void* d_out, int out_size, void* d_ws, size_t ws_size,
                              hipStream_t stream) {
  (void)in_sizes; (void)n_in; (void)out_size; (void)ws_size;
  const float* x_in = (const float*)d_in[0];
  const float* h_in = (const float*)d_in[1];
  const int* edges = (const int*)d_in[2];
  const float* eattr = (const float*)d_in[3];
  const float* emb_w = (const float*)d_in[4];
  const float* emb_b = (const float*)d_in[5];
  const float* out_w = (const float*)d_in[6];
  const float* out_b = (const float*)d_in[7];
  const float* pe_w1 = (const float*)d_in[8];
  const float* pe_b1 = (const float*)d_in[9];
  const float* pe_g1 = (const float*)d_in[10];
  const float* pe_bb1 = (const float*)d_in[11];
  const float* pe_w2 = (const float*)d_in[12];
  const float* pe_b2 = (const float*)d_in[13];
  const float* pe_g2 = (const float*)d_in[14];
  const float* pe_bb2 = (const float*)d_in[15];
  const float* px_w1 = (const float*)d_in[16];
  const float* px_b1 = (const float*)d_in[17];
  const float* px_g1 = (const float*)d_in[18];
  const float* px_bb1 = (const float*)d_in[19];
  const float* px_w2 = (const float*)d_in[20];
  const float* px_b2 = (const float*)d_in[21];
  const float* ph_w1 = (const float*)d_in[22];
  const float* ph_b1 = (const float*)d_in[23];
  const float* ph_g1 = (const float*)d_in[24];
  const float* ph_bb1 = (const float*)d_in[25];
  const float* ph_w2 = (const float*)d_in[26];
  const float* ph_b2 = (const float*)d_in[27];
  float* out = (float*)d_out;

  char* ws = (char*)d_ws;
  size_t off = 0;
  auto alloc = [&](size_t bytes) -> void* {
    void* ptr = ws + off;
    off = (off + bytes + 255) & ~(size_t)255;
    return ptr;
  };
  float* hf = (float*)alloc((size_t)NN * HD * 4);
  unsigned short* hb = (unsigned short*)alloc((size_t)NN * HD * 2);
  float* aggh = (float*)alloc((size_t)NN * HD * 4);
  float* xf = (float*)alloc((size_t)NN * 3 * 4);
  float* cinv = (float*)alloc((size_t)NN * 4);
  float* dvec = (float*)alloc((size_t)NE * 4 * 4);
  unsigned short* e8 = (unsigned short*)alloc((size_t)NE * 8 * 2);
  unsigned short* tbuf = (unsigned short*)alloc((size_t)NE * HD * 2);
  float* sc = (float*)alloc((size_t)NE * 4);
  int* deg = (int*)alloc((size_t)NN * 4);
  int* cursor = (int*)alloc((size_t)NN * 4);
  int* rowptr = (int*)alloc((size_t)(NN + 1) * 4);
  int* eids = (int*)alloc((size_t)NE * 4);
  unsigned short* w1t = (unsigned short*)alloc((size_t)NL * 9 * 4096 * 2);
  unsigned short* w2t = (unsigned short*)alloc((size_t)NL * 4 * 4096 * 2);
  unsigned short* w3t = (unsigned short*)alloc((size_t)NL * 4 * 4096 * 2);
  unsigned short* w4t = (unsigned short*)alloc((size_t)NL * 8 * 4096 * 2);
  unsigned short* w5t = (unsigned short*)alloc((size_t)NL * 4 * 4096 * 2);

  prep_zero_k<<<(NN * 3 + 255) / 256, 256, 0, stream>>>(x_in, xf, cinv, deg);
  count_k<<<(NE + 255) / 256, 256, 0, stream>>>(edges, cinv, deg);
  inv_k<<<(NN + 255) / 256, 256, 0, stream>>>(cinv);
  scan_k<<<1, 256, 0, stream>>>(deg, rowptr, cursor);
  scatter_k<<<(NE + 255) / 256, 256, 0, stream>>>(edges, cursor, eids);
  prep_w_k<<<(NL * 9 * 4096 + 255) / 256, 256, 0, stream>>>(pe_w1, w1t, 9, 261);
  prep_w_k<<<(NL * 4 * 4096 + 255) / 256, 256, 0, stream>>>(pe_w2, w2t, 4, 128);
  prep_w_k<<<(NL * 4 * 4096 + 255) / 256, 256, 0, stream>>>(px_w1, w3t, 4, 128);
  prep_w_k<<<(NL * 8 * 4096 + 255) / 256, 256, 0, stream>>>(ph_w1, w4t, 8, 256);
  prep_w_k<<<(NL * 4 * 4096 + 255) / 256, 256, 0, stream>>>(ph_w2, w5t, 4, 128);
  emb_k<<<(NN * HD + 255) / 256, 256, 0, stream>>>(h_in, emb_w, emb_b, hf, hb);

  const int egrid = NE / 128;          // 2500 (128 edges per block, 4 waves)
  const int ngrid = (NN + 63) / 64;    // 313 (64 nodes per block, 2 waves)

  for (int l = 0; l < NL; ++l) {
    prepd_k<<<(NE + 255) / 256, 256, 0, stream>>>(xf, edges, eattr, dvec, e8);
    {
      EP p{};
      p.hb = hb; p.e8 = e8; p.edges = edges;
      p.w1 = w1t + (size_t)l * 9 * 4096;
      p.w2 = w2t + (size_t)l * 4 * 4096;
      p.w3 = w3t + (size_t)l * 4 * 4096;
      p.b1 = pe_b1 + l * HD; p.g1 = pe_g1 + l * HD; p.bb1 = pe_bb1 + l * HD;
      p.b2 = pe_b2 + l * HD; p.g2 = pe_g2 + l * HD; p.bb2 = pe_bb2 + l * HD;
      p.b3 = px_b1 + l * HD; p.g3 = px_g1 + l * HD; p.bb3 = px_bb1 + l * HD;
      p.w4 = px_w2 + l * HD; p.b4 = px_b2 + l;
      p.tbuf = tbuf; p.sc = sc;
      edge_k<<<egrid, 256, 0, stream>>>(p);
    }
    gather_k<<<(NN + 3) / 4, 256, 0, stream>>>(tbuf, sc, dvec, rowptr, eids, cinv, aggh, xf);
    {
      NP p{};
      p.hf = hf; p.aggh = aggh;
      p.w4t = w4t + (size_t)l * 8 * 4096;
      p.w5t = w5t + (size_t)l * 4 * 4096;
      p.b1 = ph_b1 + l * HD; p.g1 = ph_g1 + l * HD; p.bb1 = ph_bb1 + l * HD;
      p.b5 = ph_b2 + l * HD;
      p.hf_out = hf; p.hb_out = hb;
      node_k<<<ngrid, 128, 0, stream>>>(p);
    }
  }

  outproj_k<<<(NN * OUTD + 255) / 256, 256, 0, stream>>>(hf, out_w, out_b, out);
  xcopy_k<<<(NN * 3 + 255) / 256, 256, 0, stream>>>(xf, out);
}